// Round 5
// baseline (904.911 us; speedup 1.0000x reference)
//
#include <hip/hip_runtime.h>

#define NODES 50000
#define EDGES 800000
#define EPLUS (EDGES + NODES)

// ---------- helpers ----------
__device__ __forceinline__ float ld_f(const void* p, int isbf, size_t i) {
    if (isbf) return __uint_as_float(((unsigned)((const unsigned short*)p)[i]) << 16);
    return ((const float*)p)[i];
}
__device__ __forceinline__ int ld_idx(const int* ei, int i64, int elem) {
    int v = i64 ? ei[(size_t)elem * 2] : ei[elem];   // little-endian low word
    v = v < 0 ? 0 : v;
    return v >= NODES ? NODES - 1 : v;               // defensive clamp
}

// ---------- dtype detection (1 thread) ----------
// flags[0]=1 if float tensors are bf16; flags[1]=1 if edge_index is int64
__global__ void k_detect(const unsigned* __restrict__ xw, const int* __restrict__ eiw,
                         int* __restrict__ flags) {
    if (threadIdx.x != 0 || blockIdx.x != 0) return;
    int sane = 0;
    for (int i = 0; i < 256; ++i) {
        unsigned lo = xw[i] & 0xFFFFu;               // low ushort of each dword
        int e = (int)((lo >> 7) & 0xFF);             // its bf16 exponent field
        if (lo == 0u || (e >= 90 && e <= 140)) sane++;
    }
    flags[0] = (sane > 200) ? 1 : 0;                 // bf16 data: ~256 sane; fp32 tails: ~50
    int hiz = 0;
    for (int i = 0; i < 64; ++i)
        if (eiw[2 * i + 1] == 0) hiz++;              // int64: high words all 0
    flags[1] = (hiz > 48) ? 1 : 0;
}

// ---------- input normalization to fp32 ----------
__global__ void k_cvt_x(const void* __restrict__ x, const int* __restrict__ flags,
                        float* __restrict__ out) {
    int i = blockIdx.x * 256 + threadIdx.x;
    if (i < NODES * 128) out[i] = ld_f(x, flags[0], i);
}

// pack all 12 weight tensors into one fp32 region (static sizes)
__global__ void k_cvt_w(const void* w1, const void* as1, const void* ad1, const void* b1,
                        const void* w2, const void* as2, const void* ad2, const void* b2,
                        const void* w3, const void* as3, const void* ad3, const void* b3,
                        const int* __restrict__ flags, float* __restrict__ out) {
    int tid = blockIdx.x * 256 + threadIdx.x;
    const int sz[12] = {16384,128,128,128,16384,128,128,128,2048,16,16,16};
    const void* ps[12] = {w1,as1,ad1,b1,w2,as2,ad2,b2,w3,as3,ad3,b3};
    int isbf = flags[0];
    int off = 0;
#pragma unroll
    for (int s = 0; s < 12; ++s) {
        if (tid >= off && tid < off + sz[s]) out[tid] = ld_f(ps[s], isbf, tid - off);
        off += sz[s];
    }
}
// element offsets into the packed region
#define O_W1 0
#define O_AS1 16384
#define O_AD1 16512
#define O_B1 16640
#define O_W2 16768
#define O_AS2 33152
#define O_AD2 33280
#define O_B2 33408
#define O_W3 33536
#define O_AS3 35584
#define O_AD3 35600
#define O_B3 35616
#define W_TOTAL 35632

// ---------- CSR build ----------
__global__ void k_deg(const int* __restrict__ ei, const int* __restrict__ flags,
                      int* __restrict__ deg) {
    int e = blockIdx.x * 256 + threadIdx.x;
    if (e >= EPLUS) return;
    int d = (e < EDGES) ? ld_idx(ei, flags[1], EDGES + e) : (e - EDGES);
    atomicAdd(&deg[d], 1);
}

__global__ void k_scan(int* __restrict__ deg, int* __restrict__ rowptr) {
    __shared__ int part[1024];
    const int t = threadIdx.x;
    const int CH = (NODES + 1023) / 1024;
    int base = t * CH;
    int hi = base + CH; if (hi > NODES) hi = NODES;
    int sum = 0;
    for (int i = base; i < hi; ++i) sum += deg[i];
    part[t] = sum;
    __syncthreads();
    for (int off = 1; off < 1024; off <<= 1) {
        int add = (t >= off) ? part[t - off] : 0;
        __syncthreads();
        part[t] += add;
        __syncthreads();
    }
    int running = part[t] - sum;
    for (int i = base; i < hi; ++i) {
        int old = deg[i];
        rowptr[i] = running;
        deg[i] = running;            // becomes cursor
        running += old;
    }
    if (t == 0) rowptr[NODES] = EPLUS;
}

__global__ void k_fill(const int* __restrict__ ei, const int* __restrict__ flags,
                       int* __restrict__ cursor, int* __restrict__ col) {
    int e = blockIdx.x * 256 + threadIdx.x;
    if (e >= EPLUS) return;
    int s, d;
    if (e < EDGES) {
        int i64 = flags[1];
        s = ld_idx(ei, i64, e);
        d = ld_idx(ei, i64, EDGES + e);
    } else s = d = e - EDGES;
    col[atomicAdd(&cursor[d], 1)] = s;
}

// ---------- fused GEMM + attention scores (fp32) ----------
template <int OUTC, int H, int C>
__global__ void k_gemm_att(const float* __restrict__ in, const float* __restrict__ W,
                           const float* __restrict__ a_s, const float* __restrict__ a_d,
                           float* __restrict__ hout,
                           float* __restrict__ es, float* __restrict__ ed) {
    __shared__ float lx[128];
    __shared__ float lh[OUTC];
    const int row = blockIdx.x;
    const int t = threadIdx.x;
    lx[t] = in[(size_t)row * 128 + t];
    __syncthreads();
    if (t < OUTC) {
        float acc = 0.f;
#pragma unroll 8
        for (int k = 0; k < 128; ++k)
            acc += lx[k] * W[k * OUTC + t];
        lh[t] = acc;
        hout[(size_t)row * OUTC + t] = acc;
    }
    __syncthreads();
    if (t < 2 * H) {
        int h = (t < H) ? t : (t - H);
        const float* a = (t < H) ? a_s : a_d;
        float s = 0.f;
        for (int c = 0; c < C; ++c)
            s += lh[h * C + c] * a[h * C + c];
        if (t < H) es[row * H + h] = s; else ed[row * H + h] = s;
    }
}

// ---------- gather softmax + aggregate, H=4, C=32 ----------
__global__ void k_gather4(const int* __restrict__ rowptr, const int* __restrict__ col,
                          const float* __restrict__ es, const float* __restrict__ ed,
                          const float* __restrict__ hfeat, const float* __restrict__ bias,
                          float* __restrict__ outf) {
    const int nd = blockIdx.x * 4 + (threadIdx.x >> 6);
    if (nd >= NODES) return;
    const int lane = threadIdx.x & 63;
    const int start = rowptr[nd], deg = rowptr[nd + 1] - start;

    float ed4[4], m[4], sm[4];
#pragma unroll
    for (int h = 0; h < 4; ++h) { ed4[h] = ed[nd * 4 + h]; m[h] = -1e30f; sm[h] = 0.f; }

    for (int e = lane; e < deg; e += 64) {
        int src = col[start + e];
#pragma unroll
        for (int h = 0; h < 4; ++h) {
            float v = es[src * 4 + h] + ed4[h];
            v = v > 0.f ? v : 0.2f * v;
            m[h] = fmaxf(m[h], v);
        }
    }
#pragma unroll
    for (int h = 0; h < 4; ++h)
        for (int off = 1; off < 64; off <<= 1)
            m[h] = fmaxf(m[h], __shfl_xor(m[h], off));

    for (int e = lane; e < deg; e += 64) {
        int src = col[start + e];
#pragma unroll
        for (int h = 0; h < 4; ++h) {
            float v = es[src * 4 + h] + ed4[h];
            v = v > 0.f ? v : 0.2f * v;
            sm[h] += __expf(v - m[h]);
        }
    }
#pragma unroll
    for (int h = 0; h < 4; ++h) {
        for (int off = 1; off < 64; off <<= 1)
            sm[h] += __shfl_xor(sm[h], off);
        sm[h] = 1.f / (sm[h] + 1e-16f);
    }

    const int myh = lane >> 4;                         // lane owns channels 2*lane, 2*lane+1
    const float2* __restrict__ h2 = (const float2*)hfeat;
    float a0 = 0.f, a1 = 0.f;
    for (int e = 0; e < deg; ++e) {
        int src = col[start + e];
        float v = es[src * 4 + myh] + ed4[myh];
        v = v > 0.f ? v : 0.2f * v;
        float alpha = __expf(v - m[myh]) * sm[myh];
        float2 f = h2[(size_t)src * 64 + lane];
        a0 += alpha * f.x;
        a1 += alpha * f.y;
    }
    a0 += bias[2 * lane];
    a1 += bias[2 * lane + 1];
    a0 = a0 > 0.f ? a0 : 0.f;
    a1 = a1 > 0.f ? a1 : 0.f;
    float2* __restrict__ o2 = (float2*)outf;
    o2[(size_t)nd * 64 + lane] = make_float2(a0, a1);
}

// ---------- gather H=1, C=16, writes fp32 d_out ----------
__global__ void k_gather1(const int* __restrict__ rowptr, const int* __restrict__ col,
                          const float* __restrict__ es, const float* __restrict__ ed,
                          const float* __restrict__ hfeat, const float* __restrict__ bias,
                          float* __restrict__ outf) {
    const int nd = blockIdx.x * 4 + (threadIdx.x >> 6);
    if (nd >= NODES) return;
    const int lane = threadIdx.x & 63;
    const int start = rowptr[nd], deg = rowptr[nd + 1] - start;

    const float edv = ed[nd];
    float m = -1e30f, sm = 0.f;
    for (int e = lane; e < deg; e += 64) {
        float v = es[col[start + e]] + edv;
        v = v > 0.f ? v : 0.2f * v;
        m = fmaxf(m, v);
    }
    for (int off = 1; off < 64; off <<= 1) m = fmaxf(m, __shfl_xor(m, off));
    for (int e = lane; e < deg; e += 64) {
        float v = es[col[start + e]] + edv;
        v = v > 0.f ? v : 0.2f * v;
        sm += __expf(v - m);
    }
    for (int off = 1; off < 64; off <<= 1) sm += __shfl_xor(sm, off);
    sm = 1.f / (sm + 1e-16f);

    float acc = 0.f;
    for (int e = 0; e < deg; ++e) {
        int src = col[start + e];
        float v = es[src] + edv;
        v = v > 0.f ? v : 0.2f * v;
        float alpha = __expf(v - m) * sm;
        if (lane < 16) acc += alpha * hfeat[(size_t)src * 16 + lane];
    }
    if (lane < 16)
        outf[(size_t)nd * 16 + lane] = acc + bias[lane];
}

static inline int gs(long n) { return (int)((n + 255) / 256); }

extern "C" void kernel_launch(void* const* d_in, const int* in_sizes, int n_in,
                              void* d_out, int out_size, void* d_ws, size_t ws_size,
                              hipStream_t stream) {
    const int* ei = (const int*)d_in[1];
    float* out = (float*)d_out;

    // workspace layout (~57 MB)
    char* p = (char*)d_ws;
    float* Xc     = (float*)p; p += (size_t)NODES * 128 * 4;   // 25.6 MB ping
    float* A      = (float*)p; p += (size_t)NODES * 128 * 4;   // 25.6 MB pong (h feats)
    float* es     = (float*)p; p += (size_t)NODES * 4 * 4;
    float* ed     = (float*)p; p += (size_t)NODES * 4 * 4;
    float* Wc     = (float*)p; p += (size_t)W_TOTAL * 4;
    int*   deg    = (int*)p;   p += (size_t)NODES * 4;
    int*   rowptr = (int*)p;   p += (size_t)(NODES + 1) * 4;
    int*   col    = (int*)p;   p += (size_t)EPLUS * 4;
    int*   flags  = (int*)p;

    // ---- detect dtypes, normalize inputs ----
    k_detect<<<1, 64, 0, stream>>>((const unsigned*)d_in[0], ei, flags);
    k_cvt_x<<<gs((long)NODES * 128), 256, 0, stream>>>(d_in[0], flags, Xc);
    k_cvt_w<<<gs(W_TOTAL), 256, 0, stream>>>(d_in[2], d_in[3], d_in[4], d_in[5],
                                             d_in[6], d_in[7], d_in[8], d_in[9],
                                             d_in[10], d_in[11], d_in[12], d_in[13],
                                             flags, Wc);

    // ---- CSR build ----
    hipMemsetAsync(deg, 0, (size_t)NODES * 4, stream);
    k_deg<<<gs(EPLUS), 256, 0, stream>>>(ei, flags, deg);
    k_scan<<<1, 1024, 0, stream>>>(deg, rowptr);
    k_fill<<<gs(EPLUS), 256, 0, stream>>>(ei, flags, deg, col);

    const int ggrid = (NODES + 3) / 4;

    // ---- layer 1 ----
    k_gemm_att<128, 4, 32><<<NODES, 128, 0, stream>>>(Xc, Wc + O_W1, Wc + O_AS1, Wc + O_AD1,
                                                      A, es, ed);
    k_gather4<<<ggrid, 256, 0, stream>>>(rowptr, col, es, ed, A, Wc + O_B1, Xc);
    // ---- layer 2 ----
    k_gemm_att<128, 4, 32><<<NODES, 128, 0, stream>>>(Xc, Wc + O_W2, Wc + O_AS2, Wc + O_AD2,
                                                      A, es, ed);
    k_gather4<<<ggrid, 256, 0, stream>>>(rowptr, col, es, ed, A, Wc + O_B2, Xc);
    // ---- layer 3 ----
    k_gemm_att<16, 1, 16><<<NODES, 128, 0, stream>>>(Xc, Wc + O_W3, Wc + O_AS3, Wc + O_AD3,
                                                     A, es, ed);
    k_gather1<<<ggrid, 256, 0, stream>>>(rowptr, col, es, ed, A, Wc + O_B3, out);
}

// Round 6
// 733.287 us; speedup vs baseline: 1.2340x; 1.2340x over previous
//
#include <hip/hip_runtime.h>

#define NODES 50000
#define EDGES 800000
#define EPLUS (EDGES + NODES)

// ---------- helpers ----------
__device__ __forceinline__ float ld_f(const void* p, int isbf, size_t i) {
    if (isbf) return __uint_as_float(((unsigned)((const unsigned short*)p)[i]) << 16);
    return ((const float*)p)[i];
}
__device__ __forceinline__ int ld_idx(const int* ei, int i64, int elem) {
    int v = i64 ? ei[(size_t)elem * 2] : ei[elem];   // little-endian low word
    v = v < 0 ? 0 : v;
    return v >= NODES ? NODES - 1 : v;               // defensive clamp
}

// ---------- dtype detection (1 thread) ----------
__global__ void k_detect(const unsigned* __restrict__ xw, const int* __restrict__ eiw,
                         int* __restrict__ flags) {
    if (threadIdx.x != 0 || blockIdx.x != 0) return;
    int sane = 0;
    for (int i = 0; i < 256; ++i) {
        unsigned lo = xw[i] & 0xFFFFu;
        int e = (int)((lo >> 7) & 0xFF);
        if (lo == 0u || (e >= 90 && e <= 140)) sane++;
    }
    flags[0] = (sane > 200) ? 1 : 0;
    int hiz = 0;
    for (int i = 0; i < 64; ++i)
        if (eiw[2 * i + 1] == 0) hiz++;
    flags[1] = (hiz > 48) ? 1 : 0;
}

// ---------- input normalization to fp32 ----------
__global__ void k_cvt_x(const void* __restrict__ x, const int* __restrict__ flags,
                        float* __restrict__ out) {
    int i = blockIdx.x * 256 + threadIdx.x;
    if (i < NODES * 128) out[i] = ld_f(x, flags[0], i);
}

__global__ void k_cvt_w(const void* w1, const void* as1, const void* ad1, const void* b1,
                        const void* w2, const void* as2, const void* ad2, const void* b2,
                        const void* w3, const void* as3, const void* ad3, const void* b3,
                        const int* __restrict__ flags, float* __restrict__ out) {
    int tid = blockIdx.x * 256 + threadIdx.x;
    const int sz[12] = {16384,128,128,128,16384,128,128,128,2048,16,16,16};
    const void* ps[12] = {w1,as1,ad1,b1,w2,as2,ad2,b2,w3,as3,ad3,b3};
    int isbf = flags[0];
    int off = 0;
#pragma unroll
    for (int s = 0; s < 12; ++s) {
        if (tid >= off && tid < off + sz[s]) out[tid] = ld_f(ps[s], isbf, tid - off);
        off += sz[s];
    }
}
#define O_W1 0
#define O_AS1 16384
#define O_AD1 16512
#define O_B1 16640
#define O_W2 16768
#define O_AS2 33152
#define O_AD2 33280
#define O_B2 33408
#define O_W3 33536
#define O_AS3 35584
#define O_AD3 35600
#define O_B3 35616
#define W_TOTAL 35632

// ---------- CSR build ----------
__global__ void k_deg(const int* __restrict__ ei, const int* __restrict__ flags,
                      int* __restrict__ deg) {
    int e = blockIdx.x * 256 + threadIdx.x;
    if (e >= EPLUS) return;
    int d = (e < EDGES) ? ld_idx(ei, flags[1], EDGES + e) : (e - EDGES);
    atomicAdd(&deg[d], 1);
}

__global__ void k_scan(int* __restrict__ deg, int* __restrict__ rowptr) {
    __shared__ int part[1024];
    const int t = threadIdx.x;
    const int CH = (NODES + 1023) / 1024;
    int base = t * CH;
    int hi = base + CH; if (hi > NODES) hi = NODES;
    int sum = 0;
    for (int i = base; i < hi; ++i) sum += deg[i];
    part[t] = sum;
    __syncthreads();
    for (int off = 1; off < 1024; off <<= 1) {
        int add = (t >= off) ? part[t - off] : 0;
        __syncthreads();
        part[t] += add;
        __syncthreads();
    }
    int running = part[t] - sum;
    for (int i = base; i < hi; ++i) {
        int old = deg[i];
        rowptr[i] = running;
        deg[i] = running;            // becomes cursor
        running += old;
    }
    if (t == 0) rowptr[NODES] = EPLUS;
}

__global__ void k_fill(const int* __restrict__ ei, const int* __restrict__ flags,
                       int* __restrict__ cursor, int* __restrict__ col) {
    int e = blockIdx.x * 256 + threadIdx.x;
    if (e >= EPLUS) return;
    int s, d;
    if (e < EDGES) {
        int i64 = flags[1];
        s = ld_idx(ei, i64, e);
        d = ld_idx(ei, i64, EDGES + e);
    } else s = d = e - EDGES;
    col[atomicAdd(&cursor[d], 1)] = s;
}

// ---------- GEMM 128->128 + attention scores, W cached in LDS ----------
// 3125 blocks x 256 threads; block = 16 rows; wave owns 4 rows; lane owns 2 cols
__global__ __launch_bounds__(256, 2) void k_gemm128(
        const float* __restrict__ in, const float* __restrict__ W,
        const float* __restrict__ a_s, const float* __restrict__ a_d,
        float* __restrict__ hout, float* __restrict__ es, float* __restrict__ ed) {
    __shared__ float Wl[128 * 128];     // 64 KB
    __shared__ float Xl[16][128];       // 8 KB
    const int t = threadIdx.x;
    const int rowBase = blockIdx.x * 16;

    const float4* Wg = (const float4*)W;
    float4* Wl4 = (float4*)Wl;
#pragma unroll
    for (int i = 0; i < 16; ++i) Wl4[t + 256 * i] = Wg[t + 256 * i];
    const float4* Xg = (const float4*)(in + (size_t)rowBase * 128);
    float4* Xl4 = (float4*)&Xl[0][0];
    Xl4[t] = Xg[t];
    Xl4[t + 256] = Xg[t + 256];
    __syncthreads();

    const int w = t >> 6, lane = t & 63;
    const int c0 = lane * 2;
    float acc[4][2] = {{0.f,0.f},{0.f,0.f},{0.f,0.f},{0.f,0.f}};
    const float2* W2 = (const float2*)Wl;
#pragma unroll 4
    for (int k = 0; k < 128; ++k) {
        float2 wv = W2[k * 64 + lane];          // ds_read_b64, 2 lanes/bank = free
#pragma unroll
        for (int r = 0; r < 4; ++r) {
            float xv = Xl[w * 4 + r][k];        // broadcast (same addr in wave)
            acc[r][0] += xv * wv.x;
            acc[r][1] += xv * wv.y;
        }
    }

    // epilogue: store h, fused es/ed (16-lane segmented reduce per head)
    const float a0 = a_s[c0], a1 = a_s[c0 + 1];
    const float d0 = a_d[c0], d1 = a_d[c0 + 1];
#pragma unroll
    for (int r = 0; r < 4; ++r) {
        const int row = rowBase + w * 4 + r;
        *(float2*)&hout[(size_t)row * 128 + c0] = make_float2(acc[r][0], acc[r][1]);
        float pe = acc[r][0] * a0 + acc[r][1] * a1;
        float pd = acc[r][0] * d0 + acc[r][1] * d1;
#pragma unroll
        for (int off = 1; off < 16; off <<= 1) {
            pe += __shfl_xor(pe, off);
            pd += __shfl_xor(pd, off);
        }
        if ((lane & 15) == 0) {
            const int head = lane >> 4;
            es[row * 4 + head] = pe;
            ed[row * 4 + head] = pd;
        }
    }
}

// ---------- GEMM 128->16 + scores (H=1, C=16) ----------
// 3125 blocks x 256 threads; thread = (row r = t/16, col c = t%16)
__global__ __launch_bounds__(256, 4) void k_gemm16(
        const float* __restrict__ in, const float* __restrict__ W,
        const float* __restrict__ a_s, const float* __restrict__ a_d,
        float* __restrict__ hout, float* __restrict__ es, float* __restrict__ ed) {
    __shared__ float Wl[128 * 16];      // 8 KB
    __shared__ float Xl[16][132];       // padded: banks differ across rows
    const int t = threadIdx.x;
    const int rowBase = blockIdx.x * 16;

    const float4* Wg = (const float4*)W;
    float4* Wl4 = (float4*)Wl;
    Wl4[t] = Wg[t];
    Wl4[t + 256] = Wg[t + 256];
#pragma unroll
    for (int i = 0; i < 8; ++i) {
        int idx = t + 256 * i;                  // 2048 x-elements
        Xl[idx >> 7][idx & 127] = in[(size_t)rowBase * 128 + idx];
    }
    __syncthreads();

    const int r = t >> 4, c = t & 15;
    float q0 = 0.f, q1 = 0.f, q2 = 0.f, q3 = 0.f;
#pragma unroll 8
    for (int k = 0; k < 128; k += 4) {
        q0 += Xl[r][k]     * Wl[k * 16 + c];
        q1 += Xl[r][k + 1] * Wl[(k + 1) * 16 + c];
        q2 += Xl[r][k + 2] * Wl[(k + 2) * 16 + c];
        q3 += Xl[r][k + 3] * Wl[(k + 3) * 16 + c];
    }
    const float acc = (q0 + q1) + (q2 + q3);
    const int row = rowBase + r;
    hout[(size_t)row * 16 + c] = acc;
    float pe = acc * a_s[c];
    float pd = acc * a_d[c];
#pragma unroll
    for (int off = 1; off < 16; off <<= 1) {
        pe += __shfl_xor(pe, off);
        pd += __shfl_xor(pd, off);
    }
    if (c == 0) { es[row] = pe; ed[row] = pd; }
}

// ---------- gather softmax + aggregate, H=4, C=32 ----------
__global__ void k_gather4(const int* __restrict__ rowptr, const int* __restrict__ col,
                          const float* __restrict__ es, const float* __restrict__ ed,
                          const float* __restrict__ hfeat, const float* __restrict__ bias,
                          float* __restrict__ outf) {
    const int nd = blockIdx.x * 4 + (threadIdx.x >> 6);
    if (nd >= NODES) return;
    const int lane = threadIdx.x & 63;
    const int start = rowptr[nd], deg = rowptr[nd + 1] - start;

    float ed4[4], m[4], sm[4];
#pragma unroll
    for (int h = 0; h < 4; ++h) { ed4[h] = ed[nd * 4 + h]; m[h] = -1e30f; sm[h] = 0.f; }

    for (int e = lane; e < deg; e += 64) {
        int src = col[start + e];
#pragma unroll
        for (int h = 0; h < 4; ++h) {
            float v = es[src * 4 + h] + ed4[h];
            v = v > 0.f ? v : 0.2f * v;
            m[h] = fmaxf(m[h], v);
        }
    }
#pragma unroll
    for (int h = 0; h < 4; ++h)
        for (int off = 1; off < 64; off <<= 1)
            m[h] = fmaxf(m[h], __shfl_xor(m[h], off));

    for (int e = lane; e < deg; e += 64) {
        int src = col[start + e];
#pragma unroll
        for (int h = 0; h < 4; ++h) {
            float v = es[src * 4 + h] + ed4[h];
            v = v > 0.f ? v : 0.2f * v;
            sm[h] += __expf(v - m[h]);
        }
    }
#pragma unroll
    for (int h = 0; h < 4; ++h) {
        for (int off = 1; off < 64; off <<= 1)
            sm[h] += __shfl_xor(sm[h], off);
        sm[h] = 1.f / (sm[h] + 1e-16f);
    }

    const int myh = lane >> 4;
    const float2* __restrict__ h2 = (const float2*)hfeat;
    float a0 = 0.f, a1 = 0.f;
    for (int e = 0; e < deg; ++e) {
        int src = col[start + e];
        float v = es[src * 4 + myh] + ed4[myh];
        v = v > 0.f ? v : 0.2f * v;
        float alpha = __expf(v - m[myh]) * sm[myh];
        float2 f = h2[(size_t)src * 64 + lane];
        a0 += alpha * f.x;
        a1 += alpha * f.y;
    }
    a0 += bias[2 * lane];
    a1 += bias[2 * lane + 1];
    a0 = a0 > 0.f ? a0 : 0.f;
    a1 = a1 > 0.f ? a1 : 0.f;
    float2* __restrict__ o2 = (float2*)outf;
    o2[(size_t)nd * 64 + lane] = make_float2(a0, a1);
}

// ---------- gather H=1, C=16, writes fp32 d_out ----------
__global__ void k_gather1(const int* __restrict__ rowptr, const int* __restrict__ col,
                          const float* __restrict__ es, const float* __restrict__ ed,
                          const float* __restrict__ hfeat, const float* __restrict__ bias,
                          float* __restrict__ outf) {
    const int nd = blockIdx.x * 4 + (threadIdx.x >> 6);
    if (nd >= NODES) return;
    const int lane = threadIdx.x & 63;
    const int start = rowptr[nd], deg = rowptr[nd + 1] - start;

    const float edv = ed[nd];
    float m = -1e30f, sm = 0.f;
    for (int e = lane; e < deg; e += 64) {
        float v = es[col[start + e]] + edv;
        v = v > 0.f ? v : 0.2f * v;
        m = fmaxf(m, v);
    }
    for (int off = 1; off < 64; off <<= 1) m = fmaxf(m, __shfl_xor(m, off));
    for (int e = lane; e < deg; e += 64) {
        float v = es[col[start + e]] + edv;
        v = v > 0.f ? v : 0.2f * v;
        sm += __expf(v - m);
    }
    for (int off = 1; off < 64; off <<= 1) sm += __shfl_xor(sm, off);
    sm = 1.f / (sm + 1e-16f);

    float acc = 0.f;
    for (int e = 0; e < deg; ++e) {
        int src = col[start + e];
        float v = es[src] + edv;
        v = v > 0.f ? v : 0.2f * v;
        float alpha = __expf(v - m) * sm;
        if (lane < 16) acc += alpha * hfeat[(size_t)src * 16 + lane];
    }
    if (lane < 16)
        outf[(size_t)nd * 16 + lane] = acc + bias[lane];
}

static inline int gs(long n) { return (int)((n + 255) / 256); }

extern "C" void kernel_launch(void* const* d_in, const int* in_sizes, int n_in,
                              void* d_out, int out_size, void* d_ws, size_t ws_size,
                              hipStream_t stream) {
    const int* ei = (const int*)d_in[1];
    float* out = (float*)d_out;

    // workspace layout (~57 MB)
    char* p = (char*)d_ws;
    float* Xc     = (float*)p; p += (size_t)NODES * 128 * 4;
    float* A      = (float*)p; p += (size_t)NODES * 128 * 4;
    float* es     = (float*)p; p += (size_t)NODES * 4 * 4;
    float* ed     = (float*)p; p += (size_t)NODES * 4 * 4;
    float* Wc     = (float*)p; p += (size_t)W_TOTAL * 4;
    int*   deg    = (int*)p;   p += (size_t)NODES * 4;
    int*   rowptr = (int*)p;   p += (size_t)(NODES + 1) * 4;
    int*   col    = (int*)p;   p += (size_t)EPLUS * 4;
    int*   flags  = (int*)p;

    // ---- detect dtypes, normalize inputs ----
    k_detect<<<1, 64, 0, stream>>>((const unsigned*)d_in[0], ei, flags);
    k_cvt_x<<<gs((long)NODES * 128), 256, 0, stream>>>(d_in[0], flags, Xc);
    k_cvt_w<<<gs(W_TOTAL), 256, 0, stream>>>(d_in[2], d_in[3], d_in[4], d_in[5],
                                             d_in[6], d_in[7], d_in[8], d_in[9],
                                             d_in[10], d_in[11], d_in[12], d_in[13],
                                             flags, Wc);

    // ---- CSR build ----
    hipMemsetAsync(deg, 0, (size_t)NODES * 4, stream);
    k_deg<<<gs(EPLUS), 256, 0, stream>>>(ei, flags, deg);
    k_scan<<<1, 1024, 0, stream>>>(deg, rowptr);
    k_fill<<<gs(EPLUS), 256, 0, stream>>>(ei, flags, deg, col);

    const int ggrid = (NODES + 3) / 4;
    const int gemmgrid = NODES / 16;     // 3125

    // ---- layer 1 ----
    k_gemm128<<<gemmgrid, 256, 0, stream>>>(Xc, Wc + O_W1, Wc + O_AS1, Wc + O_AD1, A, es, ed);
    k_gather4<<<ggrid, 256, 0, stream>>>(rowptr, col, es, ed, A, Wc + O_B1, Xc);
    // ---- layer 2 ----
    k_gemm128<<<gemmgrid, 256, 0, stream>>>(Xc, Wc + O_W2, Wc + O_AS2, Wc + O_AD2, A, es, ed);
    k_gather4<<<ggrid, 256, 0, stream>>>(rowptr, col, es, ed, A, Wc + O_B2, Xc);
    // ---- layer 3 ----
    k_gemm16<<<gemmgrid, 256, 0, stream>>>(Xc, Wc + O_W3, Wc + O_AS3, Wc + O_AD3, A, es, ed);
    k_gather1<<<ggrid, 256, 0, stream>>>(rowptr, col, es, ed, A, Wc + O_B3, out);
}

// Round 7
// 582.923 us; speedup vs baseline: 1.5524x; 1.2579x over previous
//
#include <hip/hip_runtime.h>

#define NODES 50000
#define EDGES 800000
#define EPLUS (EDGES + NODES)

// ---------- helpers ----------
__device__ __forceinline__ float ld_f(const void* p, int isbf, size_t i) {
    if (isbf) return __uint_as_float(((unsigned)((const unsigned short*)p)[i]) << 16);
    return ((const float*)p)[i];
}
__device__ __forceinline__ int ld_idx(const int* ei, int i64, int elem) {
    int v = i64 ? ei[(size_t)elem * 2] : ei[elem];   // little-endian low word
    v = v < 0 ? 0 : v;
    return v >= NODES ? NODES - 1 : v;               // defensive clamp
}

// ---------- dtype detection (1 thread) ----------
__global__ void k_detect(const unsigned* __restrict__ xw, const int* __restrict__ eiw,
                         int* __restrict__ flags) {
    if (threadIdx.x != 0 || blockIdx.x != 0) return;
    int sane = 0;
    for (int i = 0; i < 256; ++i) {
        unsigned lo = xw[i] & 0xFFFFu;
        int e = (int)((lo >> 7) & 0xFF);
        if (lo == 0u || (e >= 90 && e <= 140)) sane++;
    }
    flags[0] = (sane > 200) ? 1 : 0;
    int hiz = 0;
    for (int i = 0; i < 64; ++i)
        if (eiw[2 * i + 1] == 0) hiz++;
    flags[1] = (hiz > 48) ? 1 : 0;
}

// ---------- input normalization to fp32 ----------
__global__ void k_cvt_x(const void* __restrict__ x, const int* __restrict__ flags,
                        float* __restrict__ out) {
    int i = blockIdx.x * 256 + threadIdx.x;
    if (i < NODES * 128) out[i] = ld_f(x, flags[0], i);
}

__global__ void k_cvt_w(const void* w1, const void* as1, const void* ad1, const void* b1,
                        const void* w2, const void* as2, const void* ad2, const void* b2,
                        const void* w3, const void* as3, const void* ad3, const void* b3,
                        const int* __restrict__ flags, float* __restrict__ out) {
    int tid = blockIdx.x * 256 + threadIdx.x;
    const int sz[12] = {16384,128,128,128,16384,128,128,128,2048,16,16,16};
    const void* ps[12] = {w1,as1,ad1,b1,w2,as2,ad2,b2,w3,as3,ad3,b3};
    int isbf = flags[0];
    int off = 0;
#pragma unroll
    for (int s = 0; s < 12; ++s) {
        if (tid >= off && tid < off + sz[s]) out[tid] = ld_f(ps[s], isbf, tid - off);
        off += sz[s];
    }
}
#define O_W1 0
#define O_AS1 16384
#define O_AD1 16512
#define O_B1 16640
#define O_W2 16768
#define O_AS2 33152
#define O_AD2 33280
#define O_B2 33408
#define O_W3 33536
#define O_AS3 35584
#define O_AD3 35600
#define O_B3 35616
#define W_TOTAL 35632

// ---------- CSR build ----------
__global__ void k_deg(const int* __restrict__ ei, const int* __restrict__ flags,
                      int* __restrict__ deg) {
    int e = blockIdx.x * 256 + threadIdx.x;
    if (e >= EPLUS) return;
    int d = (e < EDGES) ? ld_idx(ei, flags[1], EDGES + e) : (e - EDGES);
    atomicAdd(&deg[d], 1);
}

__global__ void k_scan(int* __restrict__ deg, int* __restrict__ rowptr) {
    __shared__ int part[1024];
    const int t = threadIdx.x;
    const int CH = (NODES + 1023) / 1024;
    int base = t * CH;
    int hi = base + CH; if (hi > NODES) hi = NODES;
    int sum = 0;
    for (int i = base; i < hi; ++i) sum += deg[i];
    part[t] = sum;
    __syncthreads();
    for (int off = 1; off < 1024; off <<= 1) {
        int add = (t >= off) ? part[t - off] : 0;
        __syncthreads();
        part[t] += add;
        __syncthreads();
    }
    int running = part[t] - sum;
    for (int i = base; i < hi; ++i) {
        int old = deg[i];
        rowptr[i] = running;
        deg[i] = running;            // becomes cursor
        running += old;
    }
    if (t == 0) rowptr[NODES] = EPLUS;
}

__global__ void k_fill(const int* __restrict__ ei, const int* __restrict__ flags,
                       int* __restrict__ cursor, int* __restrict__ col) {
    int e = blockIdx.x * 256 + threadIdx.x;
    if (e >= EPLUS) return;
    int s, d;
    if (e < EDGES) {
        int i64 = flags[1];
        s = ld_idx(ei, i64, e);
        d = ld_idx(ei, i64, EDGES + e);
    } else s = d = e - EDGES;
    col[atomicAdd(&cursor[d], 1)] = s;
}

// ---------- GEMM 128->128 + attention scores, W cached in LDS ----------
__global__ __launch_bounds__(256, 2) void k_gemm128(
        const float* __restrict__ in, const float* __restrict__ W,
        const float* __restrict__ a_s, const float* __restrict__ a_d,
        float* __restrict__ hout, float* __restrict__ es, float* __restrict__ ed) {
    __shared__ float Wl[128 * 128];     // 64 KB
    __shared__ float Xl[16][128];       // 8 KB
    const int t = threadIdx.x;
    const int rowBase = blockIdx.x * 16;

    const float4* Wg = (const float4*)W;
    float4* Wl4 = (float4*)Wl;
#pragma unroll
    for (int i = 0; i < 16; ++i) Wl4[t + 256 * i] = Wg[t + 256 * i];
    const float4* Xg = (const float4*)(in + (size_t)rowBase * 128);
    float4* Xl4 = (float4*)&Xl[0][0];
    Xl4[t] = Xg[t];
    Xl4[t + 256] = Xg[t + 256];
    __syncthreads();

    const int w = t >> 6, lane = t & 63;
    const int c0 = lane * 2;
    float acc[4][2] = {{0.f,0.f},{0.f,0.f},{0.f,0.f},{0.f,0.f}};
    const float2* W2 = (const float2*)Wl;
#pragma unroll 4
    for (int k = 0; k < 128; ++k) {
        float2 wv = W2[k * 64 + lane];
#pragma unroll
        for (int r = 0; r < 4; ++r) {
            float xv = Xl[w * 4 + r][k];
            acc[r][0] += xv * wv.x;
            acc[r][1] += xv * wv.y;
        }
    }

    const float a0 = a_s[c0], a1 = a_s[c0 + 1];
    const float d0 = a_d[c0], d1 = a_d[c0 + 1];
#pragma unroll
    for (int r = 0; r < 4; ++r) {
        const int row = rowBase + w * 4 + r;
        *(float2*)&hout[(size_t)row * 128 + c0] = make_float2(acc[r][0], acc[r][1]);
        float pe = acc[r][0] * a0 + acc[r][1] * a1;
        float pd = acc[r][0] * d0 + acc[r][1] * d1;
#pragma unroll
        for (int off = 1; off < 16; off <<= 1) {
            pe += __shfl_xor(pe, off);
            pd += __shfl_xor(pd, off);
        }
        if ((lane & 15) == 0) {
            const int head = lane >> 4;
            es[row * 4 + head] = pe;
            ed[row * 4 + head] = pd;
        }
    }
}

// ---------- GEMM 128->16 + scores (H=1, C=16) ----------
__global__ __launch_bounds__(256, 4) void k_gemm16(
        const float* __restrict__ in, const float* __restrict__ W,
        const float* __restrict__ a_s, const float* __restrict__ a_d,
        float* __restrict__ hout, float* __restrict__ es, float* __restrict__ ed) {
    __shared__ float Wl[128 * 16];
    __shared__ float Xl[16][132];
    const int t = threadIdx.x;
    const int rowBase = blockIdx.x * 16;

    const float4* Wg = (const float4*)W;
    float4* Wl4 = (float4*)Wl;
    Wl4[t] = Wg[t];
    Wl4[t + 256] = Wg[t + 256];
#pragma unroll
    for (int i = 0; i < 8; ++i) {
        int idx = t + 256 * i;
        Xl[idx >> 7][idx & 127] = in[(size_t)rowBase * 128 + idx];
    }
    __syncthreads();

    const int r = t >> 4, c = t & 15;
    float q0 = 0.f, q1 = 0.f, q2 = 0.f, q3 = 0.f;
#pragma unroll 8
    for (int k = 0; k < 128; k += 4) {
        q0 += Xl[r][k]     * Wl[k * 16 + c];
        q1 += Xl[r][k + 1] * Wl[(k + 1) * 16 + c];
        q2 += Xl[r][k + 2] * Wl[(k + 2) * 16 + c];
        q3 += Xl[r][k + 3] * Wl[(k + 3) * 16 + c];
    }
    const float acc = (q0 + q1) + (q2 + q3);
    const int row = rowBase + r;
    hout[(size_t)row * 16 + c] = acc;
    float pe = acc * a_s[c];
    float pd = acc * a_d[c];
#pragma unroll
    for (int off = 1; off < 16; off <<= 1) {
        pe += __shfl_xor(pe, off);
        pd += __shfl_xor(pd, off);
    }
    if (c == 0) { es[row] = pe; ed[row] = pd; }
}

// ---------- gather softmax + aggregate, H=4, C=32 ----------
// wave per dst node; pass3: 2 edge-subgroups x 32 lanes, lane owns 4 channels
__global__ void k_gather4(const int* __restrict__ rowptr, const int* __restrict__ col,
                          const float* __restrict__ es, const float* __restrict__ ed,
                          const float* __restrict__ hfeat, const float* __restrict__ bias,
                          float* __restrict__ outf) {
    const int nd = blockIdx.x * 4 + (threadIdx.x >> 6);
    if (nd >= NODES) return;
    const int lane = threadIdx.x & 63;
    const int start = rowptr[nd], deg = rowptr[nd + 1] - start;

    float ed4[4], m[4], sm[4];
#pragma unroll
    for (int h = 0; h < 4; ++h) { ed4[h] = ed[nd * 4 + h]; m[h] = -1e30f; sm[h] = 0.f; }

    for (int e = lane; e < deg; e += 64) {
        int src = col[start + e];
#pragma unroll
        for (int h = 0; h < 4; ++h) {
            float v = es[src * 4 + h] + ed4[h];
            v = v > 0.f ? v : 0.2f * v;
            m[h] = fmaxf(m[h], v);
        }
    }
#pragma unroll
    for (int h = 0; h < 4; ++h)
        for (int off = 1; off < 64; off <<= 1)
            m[h] = fmaxf(m[h], __shfl_xor(m[h], off));

    for (int e = lane; e < deg; e += 64) {
        int src = col[start + e];
#pragma unroll
        for (int h = 0; h < 4; ++h) {
            float v = es[src * 4 + h] + ed4[h];
            v = v > 0.f ? v : 0.2f * v;
            sm[h] += __expf(v - m[h]);
        }
    }
#pragma unroll
    for (int h = 0; h < 4; ++h) {
        for (int off = 1; off < 64; off <<= 1)
            sm[h] += __shfl_xor(sm[h], off);
        sm[h] = 1.f / (sm[h] + 1e-16f);
    }

    // pass 3: subgroup esub handles edges esub, esub+2, ...; unroll 2
    const int esub = lane >> 5;
    const int cl = lane & 31;            // lane owns channels 4*cl .. 4*cl+3
    const int myh = cl >> 3;
    const float mh = m[myh], smh = sm[myh], edh = ed4[myh];
    const float4* __restrict__ h4 = (const float4*)hfeat;   // row stride 32
    float ax = 0.f, ay = 0.f, az = 0.f, aw = 0.f;

    int e = esub;
    for (; e + 2 < deg; e += 4) {
        int s0 = col[start + e];
        int s1 = col[start + e + 2];
        float4 f0 = h4[(size_t)s0 * 32 + cl];
        float4 f1 = h4[(size_t)s1 * 32 + cl];
        float v0 = es[s0 * 4 + myh] + edh; v0 = v0 > 0.f ? v0 : 0.2f * v0;
        float v1 = es[s1 * 4 + myh] + edh; v1 = v1 > 0.f ? v1 : 0.2f * v1;
        float al0 = __expf(v0 - mh) * smh;
        float al1 = __expf(v1 - mh) * smh;
        ax += al0 * f0.x + al1 * f1.x;
        ay += al0 * f0.y + al1 * f1.y;
        az += al0 * f0.z + al1 * f1.z;
        aw += al0 * f0.w + al1 * f1.w;
    }
    for (; e < deg; e += 2) {
        int s0 = col[start + e];
        float4 f0 = h4[(size_t)s0 * 32 + cl];
        float v0 = es[s0 * 4 + myh] + edh; v0 = v0 > 0.f ? v0 : 0.2f * v0;
        float al0 = __expf(v0 - mh) * smh;
        ax += al0 * f0.x;
        ay += al0 * f0.y;
        az += al0 * f0.z;
        aw += al0 * f0.w;
    }
    // merge the two edge-subgroups
    ax += __shfl_xor(ax, 32);
    ay += __shfl_xor(ay, 32);
    az += __shfl_xor(az, 32);
    aw += __shfl_xor(aw, 32);

    if (esub == 0) {
        float4 b = ((const float4*)bias)[cl];
        ax += b.x; ay += b.y; az += b.z; aw += b.w;
        ax = ax > 0.f ? ax : 0.f;
        ay = ay > 0.f ? ay : 0.f;
        az = az > 0.f ? az : 0.f;
        aw = aw > 0.f ? aw : 0.f;
        ((float4*)outf)[(size_t)nd * 32 + cl] = make_float4(ax, ay, az, aw);
    }
}

// ---------- gather H=1, C=16, writes fp32 d_out ----------
// pass3: 4 edge-subgroups x 16 lanes
__global__ void k_gather1(const int* __restrict__ rowptr, const int* __restrict__ col,
                          const float* __restrict__ es, const float* __restrict__ ed,
                          const float* __restrict__ hfeat, const float* __restrict__ bias,
                          float* __restrict__ outf) {
    const int nd = blockIdx.x * 4 + (threadIdx.x >> 6);
    if (nd >= NODES) return;
    const int lane = threadIdx.x & 63;
    const int start = rowptr[nd], deg = rowptr[nd + 1] - start;

    const float edv = ed[nd];
    float m = -1e30f, sm = 0.f;
    for (int e = lane; e < deg; e += 64) {
        float v = es[col[start + e]] + edv;
        v = v > 0.f ? v : 0.2f * v;
        m = fmaxf(m, v);
    }
    for (int off = 1; off < 64; off <<= 1) m = fmaxf(m, __shfl_xor(m, off));
    for (int e = lane; e < deg; e += 64) {
        float v = es[col[start + e]] + edv;
        v = v > 0.f ? v : 0.2f * v;
        sm += __expf(v - m);
    }
    for (int off = 1; off < 64; off <<= 1) sm += __shfl_xor(sm, off);
    sm = 1.f / (sm + 1e-16f);

    const int esub = lane >> 4;          // 0..3
    const int c = lane & 15;
    float acc = 0.f;
    int e = esub;
    for (; e + 4 < deg; e += 8) {
        int s0 = col[start + e];
        int s1 = col[start + e + 4];
        float f0 = hfeat[(size_t)s0 * 16 + c];
        float f1 = hfeat[(size_t)s1 * 16 + c];
        float v0 = es[s0] + edv; v0 = v0 > 0.f ? v0 : 0.2f * v0;
        float v1 = es[s1] + edv; v1 = v1 > 0.f ? v1 : 0.2f * v1;
        acc += __expf(v0 - m) * sm * f0 + __expf(v1 - m) * sm * f1;
    }
    for (; e < deg; e += 4) {
        int s0 = col[start + e];
        float f0 = hfeat[(size_t)s0 * 16 + c];
        float v0 = es[s0] + edv; v0 = v0 > 0.f ? v0 : 0.2f * v0;
        acc += __expf(v0 - m) * sm * f0;
    }
    acc += __shfl_xor(acc, 32);
    acc += __shfl_xor(acc, 16);
    if (lane < 16)
        outf[(size_t)nd * 16 + lane] = acc + bias[lane];
}

static inline int gs(long n) { return (int)((n + 255) / 256); }

extern "C" void kernel_launch(void* const* d_in, const int* in_sizes, int n_in,
                              void* d_out, int out_size, void* d_ws, size_t ws_size,
                              hipStream_t stream) {
    const int* ei = (const int*)d_in[1];
    float* out = (float*)d_out;

    char* p = (char*)d_ws;
    float* Xc     = (float*)p; p += (size_t)NODES * 128 * 4;
    float* A      = (float*)p; p += (size_t)NODES * 128 * 4;
    float* es     = (float*)p; p += (size_t)NODES * 4 * 4;
    float* ed     = (float*)p; p += (size_t)NODES * 4 * 4;
    float* Wc     = (float*)p; p += (size_t)W_TOTAL * 4;
    int*   deg    = (int*)p;   p += (size_t)NODES * 4;
    int*   rowptr = (int*)p;   p += (size_t)(NODES + 1) * 4;
    int*   col    = (int*)p;   p += (size_t)EPLUS * 4;
    int*   flags  = (int*)p;

    k_detect<<<1, 64, 0, stream>>>((const unsigned*)d_in[0], ei, flags);
    k_cvt_x<<<gs((long)NODES * 128), 256, 0, stream>>>(d_in[0], flags, Xc);
    k_cvt_w<<<gs(W_TOTAL), 256, 0, stream>>>(d_in[2], d_in[3], d_in[4], d_in[5],
                                             d_in[6], d_in[7], d_in[8], d_in[9],
                                             d_in[10], d_in[11], d_in[12], d_in[13],
                                             flags, Wc);

    hipMemsetAsync(deg, 0, (size_t)NODES * 4, stream);
    k_deg<<<gs(EPLUS), 256, 0, stream>>>(ei, flags, deg);
    k_scan<<<1, 1024, 0, stream>>>(deg, rowptr);
    k_fill<<<gs(EPLUS), 256, 0, stream>>>(ei, flags, deg, col);

    const int ggrid = (NODES + 3) / 4;
    const int gemmgrid = NODES / 16;

    k_gemm128<<<gemmgrid, 256, 0, stream>>>(Xc, Wc + O_W1, Wc + O_AS1, Wc + O_AD1, A, es, ed);
    k_gather4<<<ggrid, 256, 0, stream>>>(rowptr, col, es, ed, A, Wc + O_B1, Xc);
    k_gemm128<<<gemmgrid, 256, 0, stream>>>(Xc, Wc + O_W2, Wc + O_AS2, Wc + O_AD2, A, es, ed);
    k_gather4<<<ggrid, 256, 0, stream>>>(rowptr, col, es, ed, A, Wc + O_B2, Xc);
    k_gemm16<<<gemmgrid, 256, 0, stream>>>(Xc, Wc + O_W3, Wc + O_AS3, Wc + O_AD3, A, es, ed);
    k_gather1<<<ggrid, 256, 0, stream>>>(rowptr, col, es, ed, A, Wc + O_B3, out);
}

// Round 8
// 494.440 us; speedup vs baseline: 1.8302x; 1.1790x over previous
//
#include <hip/hip_runtime.h>

#define NODES 50000
#define EDGES 800000
#define EPLUS (EDGES + NODES)
#define NBLK 196   // ceil(NODES/256)

// ---------- helpers ----------
__device__ __forceinline__ float ld_f(const void* p, int isbf, size_t i) {
    if (isbf) return __uint_as_float(((unsigned)((const unsigned short*)p)[i]) << 16);
    return ((const float*)p)[i];
}
__device__ __forceinline__ int ld_idx(const int* ei, int i64, int elem) {
    int v = i64 ? ei[(size_t)elem * 2] : ei[elem];   // little-endian low word
    v = v < 0 ? 0 : v;
    return v >= NODES ? NODES - 1 : v;               // defensive clamp
}

// ---------- dtype detection (1 thread) ----------
__global__ void k_detect(const unsigned* __restrict__ xw, const int* __restrict__ eiw,
                         int* __restrict__ flags) {
    if (threadIdx.x != 0 || blockIdx.x != 0) return;
    int sane = 0;
    for (int i = 0; i < 256; ++i) {
        unsigned lo = xw[i] & 0xFFFFu;
        int e = (int)((lo >> 7) & 0xFF);
        if (lo == 0u || (e >= 90 && e <= 140)) sane++;
    }
    flags[0] = (sane > 200) ? 1 : 0;
    int hiz = 0;
    for (int i = 0; i < 64; ++i)
        if (eiw[2 * i + 1] == 0) hiz++;
    flags[1] = (hiz > 48) ? 1 : 0;
}

// ---------- input normalization to fp32 ----------
__global__ void k_cvt_x(const void* __restrict__ x, const int* __restrict__ flags,
                        float* __restrict__ out) {
    int i = blockIdx.x * 256 + threadIdx.x;
    if (i < NODES * 128) out[i] = ld_f(x, flags[0], i);
}

__global__ void k_cvt_w(const void* w1, const void* as1, const void* ad1, const void* b1,
                        const void* w2, const void* as2, const void* ad2, const void* b2,
                        const void* w3, const void* as3, const void* ad3, const void* b3,
                        const int* __restrict__ flags, float* __restrict__ out) {
    int tid = blockIdx.x * 256 + threadIdx.x;
    const int sz[12] = {16384,128,128,128,16384,128,128,128,2048,16,16,16};
    const void* ps[12] = {w1,as1,ad1,b1,w2,as2,ad2,b2,w3,as3,ad3,b3};
    int isbf = flags[0];
    int off = 0;
#pragma unroll
    for (int s = 0; s < 12; ++s) {
        if (tid >= off && tid < off + sz[s]) out[tid] = ld_f(ps[s], isbf, tid - off);
        off += sz[s];
    }
}
#define O_W1 0
#define O_AS1 16384
#define O_AD1 16512
#define O_B1 16640
#define O_W2 16768
#define O_AS2 33152
#define O_AD2 33280
#define O_B2 33408
#define O_W3 33536
#define O_AS3 35584
#define O_AD3 35600
#define O_B3 35616
#define W_TOTAL 35632

// ---------- CSR build ----------
__global__ void k_deg(const int* __restrict__ ei, const int* __restrict__ flags,
                      int* __restrict__ deg) {
    int e = blockIdx.x * 256 + threadIdx.x;
    if (e >= EPLUS) return;
    int d = (e < EDGES) ? ld_idx(ei, flags[1], EDGES + e) : (e - EDGES);
    atomicAdd(&deg[d], 1);
}

// stage A: per-block sums of deg
__global__ void k_scan_a(const int* __restrict__ deg, int* __restrict__ partial) {
    __shared__ int ws[4];
    const int t = threadIdx.x;
    int idx = blockIdx.x * 256 + t;
    int v = (idx < NODES) ? deg[idx] : 0;
#pragma unroll
    for (int off = 1; off < 64; off <<= 1) v += __shfl_xor(v, off);
    if ((t & 63) == 0) ws[t >> 6] = v;
    __syncthreads();
    if (t == 0) partial[blockIdx.x] = ws[0] + ws[1] + ws[2] + ws[3];
}

// stage B: exclusive scan of NBLK partials (1 block, 256 threads)
__global__ void k_scan_b(int* __restrict__ partial) {
    __shared__ int s[256];
    const int t = threadIdx.x;
    int v = (t < NBLK) ? partial[t] : 0;
    s[t] = v;
    __syncthreads();
#pragma unroll
    for (int off = 1; off < 256; off <<= 1) {
        int add = (t >= off) ? s[t - off] : 0;
        __syncthreads();
        s[t] += add;
        __syncthreads();
    }
    if (t < NBLK) partial[t] = s[t] - v;   // exclusive
}

// stage C: per-block exclusive scan + offset; writes rowptr and cursor
__global__ void k_scan_c(int* __restrict__ deg, const int* __restrict__ partial,
                         int* __restrict__ rowptr) {
    __shared__ int s[256];
    const int t = threadIdx.x;
    const int idx = blockIdx.x * 256 + t;
    int v = (idx < NODES) ? deg[idx] : 0;
    s[t] = v;
    __syncthreads();
#pragma unroll
    for (int off = 1; off < 256; off <<= 1) {
        int add = (t >= off) ? s[t - off] : 0;
        __syncthreads();
        s[t] += add;
        __syncthreads();
    }
    int ex = partial[blockIdx.x] + s[t] - v;
    if (idx < NODES) {
        rowptr[idx] = ex;
        deg[idx] = ex;                     // becomes cursor
    } else if (idx == NODES) {
        rowptr[NODES] = ex;                // == EPLUS
    }
}

__global__ void k_fill(const int* __restrict__ ei, const int* __restrict__ flags,
                       int* __restrict__ cursor, int* __restrict__ col) {
    int e = blockIdx.x * 256 + threadIdx.x;
    if (e >= EPLUS) return;
    int s, d;
    if (e < EDGES) {
        int i64 = flags[1];
        s = ld_idx(ei, i64, e);
        d = ld_idx(ei, i64, EDGES + e);
    } else s = d = e - EDGES;
    col[atomicAdd(&cursor[d], 1)] = s;
}

// ---------- GEMM 128->128 + attention scores, W cached in LDS ----------
__global__ __launch_bounds__(256, 2) void k_gemm128(
        const float* __restrict__ in, const float* __restrict__ W,
        const float* __restrict__ a_s, const float* __restrict__ a_d,
        float* __restrict__ hout, float* __restrict__ es, float* __restrict__ ed) {
    __shared__ float Wl[128 * 128];     // 64 KB
    __shared__ float Xl[16][128];       // 8 KB
    const int t = threadIdx.x;
    const int rowBase = blockIdx.x * 16;

    const float4* Wg = (const float4*)W;
    float4* Wl4 = (float4*)Wl;
#pragma unroll
    for (int i = 0; i < 16; ++i) Wl4[t + 256 * i] = Wg[t + 256 * i];
    const float4* Xg = (const float4*)(in + (size_t)rowBase * 128);
    float4* Xl4 = (float4*)&Xl[0][0];
    Xl4[t] = Xg[t];
    Xl4[t + 256] = Xg[t + 256];
    __syncthreads();

    const int w = t >> 6, lane = t & 63;
    const int c0 = lane * 2;
    float acc[4][2] = {{0.f,0.f},{0.f,0.f},{0.f,0.f},{0.f,0.f}};
    const float2* W2 = (const float2*)Wl;
#pragma unroll 4
    for (int k = 0; k < 128; ++k) {
        float2 wv = W2[k * 64 + lane];
#pragma unroll
        for (int r = 0; r < 4; ++r) {
            float xv = Xl[w * 4 + r][k];
            acc[r][0] += xv * wv.x;
            acc[r][1] += xv * wv.y;
        }
    }

    const float a0 = a_s[c0], a1 = a_s[c0 + 1];
    const float d0 = a_d[c0], d1 = a_d[c0 + 1];
#pragma unroll
    for (int r = 0; r < 4; ++r) {
        const int row = rowBase + w * 4 + r;
        *(float2*)&hout[(size_t)row * 128 + c0] = make_float2(acc[r][0], acc[r][1]);
        float pe = acc[r][0] * a0 + acc[r][1] * a1;
        float pd = acc[r][0] * d0 + acc[r][1] * d1;
#pragma unroll
        for (int off = 1; off < 16; off <<= 1) {
            pe += __shfl_xor(pe, off);
            pd += __shfl_xor(pd, off);
        }
        if ((lane & 15) == 0) {
            const int head = lane >> 4;
            es[row * 4 + head] = pe;
            ed[row * 4 + head] = pd;
        }
    }
}

// ---------- GEMM 128->16 + scores (H=1, C=16) ----------
__global__ __launch_bounds__(256, 4) void k_gemm16(
        const float* __restrict__ in, const float* __restrict__ W,
        const float* __restrict__ a_s, const float* __restrict__ a_d,
        float* __restrict__ hout, float* __restrict__ es, float* __restrict__ ed) {
    __shared__ float Wl[128 * 16];
    __shared__ float Xl[16][132];
    const int t = threadIdx.x;
    const int rowBase = blockIdx.x * 16;

    const float4* Wg = (const float4*)W;
    float4* Wl4 = (float4*)Wl;
    Wl4[t] = Wg[t];
    Wl4[t + 256] = Wg[t + 256];
#pragma unroll
    for (int i = 0; i < 8; ++i) {
        int idx = t + 256 * i;
        Xl[idx >> 7][idx & 127] = in[(size_t)rowBase * 128 + idx];
    }
    __syncthreads();

    const int r = t >> 4, c = t & 15;
    float q0 = 0.f, q1 = 0.f, q2 = 0.f, q3 = 0.f;
#pragma unroll 8
    for (int k = 0; k < 128; k += 4) {
        q0 += Xl[r][k]     * Wl[k * 16 + c];
        q1 += Xl[r][k + 1] * Wl[(k + 1) * 16 + c];
        q2 += Xl[r][k + 2] * Wl[(k + 2) * 16 + c];
        q3 += Xl[r][k + 3] * Wl[(k + 3) * 16 + c];
    }
    const float acc = (q0 + q1) + (q2 + q3);
    const int row = rowBase + r;
    hout[(size_t)row * 16 + c] = acc;
    float pe = acc * a_s[c];
    float pd = acc * a_d[c];
#pragma unroll
    for (int off = 1; off < 16; off <<= 1) {
        pe += __shfl_xor(pe, off);
        pd += __shfl_xor(pd, off);
    }
    if (c == 0) { es[row] = pe; ed[row] = pd; }
}

// ---------- gather softmax + aggregate, H=4, C=32 ----------
__global__ void k_gather4(const int* __restrict__ rowptr, const int* __restrict__ col,
                          const float* __restrict__ es, const float* __restrict__ ed,
                          const float* __restrict__ hfeat, const float* __restrict__ bias,
                          float* __restrict__ outf) {
    const int nd = blockIdx.x * 4 + (threadIdx.x >> 6);
    if (nd >= NODES) return;
    const int lane = threadIdx.x & 63;
    const int start = rowptr[nd], deg = rowptr[nd + 1] - start;

    float ed4[4], m[4], sm[4];
#pragma unroll
    for (int h = 0; h < 4; ++h) { ed4[h] = ed[nd * 4 + h]; m[h] = -1e30f; sm[h] = 0.f; }

    for (int e = lane; e < deg; e += 64) {
        int src = col[start + e];
#pragma unroll
        for (int h = 0; h < 4; ++h) {
            float v = es[src * 4 + h] + ed4[h];
            v = v > 0.f ? v : 0.2f * v;
            m[h] = fmaxf(m[h], v);
        }
    }
#pragma unroll
    for (int h = 0; h < 4; ++h)
        for (int off = 1; off < 64; off <<= 1)
            m[h] = fmaxf(m[h], __shfl_xor(m[h], off));

    for (int e = lane; e < deg; e += 64) {
        int src = col[start + e];
#pragma unroll
        for (int h = 0; h < 4; ++h) {
            float v = es[src * 4 + h] + ed4[h];
            v = v > 0.f ? v : 0.2f * v;
            sm[h] += __expf(v - m[h]);
        }
    }
#pragma unroll
    for (int h = 0; h < 4; ++h) {
        for (int off = 1; off < 64; off <<= 1)
            sm[h] += __shfl_xor(sm[h], off);
        sm[h] = 1.f / (sm[h] + 1e-16f);
    }

    const int esub = lane >> 5;
    const int cl = lane & 31;
    const int myh = cl >> 3;
    const float mh = m[myh], smh = sm[myh], edh = ed4[myh];
    const float4* __restrict__ h4 = (const float4*)hfeat;
    float ax = 0.f, ay = 0.f, az = 0.f, aw = 0.f;

    int e = esub;
    for (; e + 2 < deg; e += 4) {
        int s0 = col[start + e];
        int s1 = col[start + e + 2];
        float4 f0 = h4[(size_t)s0 * 32 + cl];
        float4 f1 = h4[(size_t)s1 * 32 + cl];
        float v0 = es[s0 * 4 + myh] + edh; v0 = v0 > 0.f ? v0 : 0.2f * v0;
        float v1 = es[s1 * 4 + myh] + edh; v1 = v1 > 0.f ? v1 : 0.2f * v1;
        float al0 = __expf(v0 - mh) * smh;
        float al1 = __expf(v1 - mh) * smh;
        ax += al0 * f0.x + al1 * f1.x;
        ay += al0 * f0.y + al1 * f1.y;
        az += al0 * f0.z + al1 * f1.z;
        aw += al0 * f0.w + al1 * f1.w;
    }
    for (; e < deg; e += 2) {
        int s0 = col[start + e];
        float4 f0 = h4[(size_t)s0 * 32 + cl];
        float v0 = es[s0 * 4 + myh] + edh; v0 = v0 > 0.f ? v0 : 0.2f * v0;
        float al0 = __expf(v0 - mh) * smh;
        ax += al0 * f0.x;
        ay += al0 * f0.y;
        az += al0 * f0.z;
        aw += al0 * f0.w;
    }
    ax += __shfl_xor(ax, 32);
    ay += __shfl_xor(ay, 32);
    az += __shfl_xor(az, 32);
    aw += __shfl_xor(aw, 32);

    if (esub == 0) {
        float4 b = ((const float4*)bias)[cl];
        ax += b.x; ay += b.y; az += b.z; aw += b.w;
        ax = ax > 0.f ? ax : 0.f;
        ay = ay > 0.f ? ay : 0.f;
        az = az > 0.f ? az : 0.f;
        aw = aw > 0.f ? aw : 0.f;
        ((float4*)outf)[(size_t)nd * 32 + cl] = make_float4(ax, ay, az, aw);
    }
}

// ---------- gather H=1, C=16, writes fp32 d_out ----------
__global__ void k_gather1(const int* __restrict__ rowptr, const int* __restrict__ col,
                          const float* __restrict__ es, const float* __restrict__ ed,
                          const float* __restrict__ hfeat, const float* __restrict__ bias,
                          float* __restrict__ outf) {
    const int nd = blockIdx.x * 4 + (threadIdx.x >> 6);
    if (nd >= NODES) return;
    const int lane = threadIdx.x & 63;
    const int start = rowptr[nd], deg = rowptr[nd + 1] - start;

    const float edv = ed[nd];
    float m = -1e30f, sm = 0.f;
    for (int e = lane; e < deg; e += 64) {
        float v = es[col[start + e]] + edv;
        v = v > 0.f ? v : 0.2f * v;
        m = fmaxf(m, v);
    }
    for (int off = 1; off < 64; off <<= 1) m = fmaxf(m, __shfl_xor(m, off));
    for (int e = lane; e < deg; e += 64) {
        float v = es[col[start + e]] + edv;
        v = v > 0.f ? v : 0.2f * v;
        sm += __expf(v - m);
    }
    for (int off = 1; off < 64; off <<= 1) sm += __shfl_xor(sm, off);
    sm = 1.f / (sm + 1e-16f);

    const int esub = lane >> 4;
    const int c = lane & 15;
    float acc = 0.f;
    int e = esub;
    for (; e + 4 < deg; e += 8) {
        int s0 = col[start + e];
        int s1 = col[start + e + 4];
        float f0 = hfeat[(size_t)s0 * 16 + c];
        float f1 = hfeat[(size_t)s1 * 16 + c];
        float v0 = es[s0] + edv; v0 = v0 > 0.f ? v0 : 0.2f * v0;
        float v1 = es[s1] + edv; v1 = v1 > 0.f ? v1 : 0.2f * v1;
        acc += __expf(v0 - m) * sm * f0 + __expf(v1 - m) * sm * f1;
    }
    for (; e < deg; e += 4) {
        int s0 = col[start + e];
        float f0 = hfeat[(size_t)s0 * 16 + c];
        float v0 = es[s0] + edv; v0 = v0 > 0.f ? v0 : 0.2f * v0;
        acc += __expf(v0 - m) * sm * f0;
    }
    acc += __shfl_xor(acc, 32);
    acc += __shfl_xor(acc, 16);
    if (lane < 16)
        outf[(size_t)nd * 16 + lane] = acc + bias[lane];
}

static inline int gs(long n) { return (int)((n + 255) / 256); }

extern "C" void kernel_launch(void* const* d_in, const int* in_sizes, int n_in,
                              void* d_out, int out_size, void* d_ws, size_t ws_size,
                              hipStream_t stream) {
    const int* ei = (const int*)d_in[1];
    float* out = (float*)d_out;

    char* p = (char*)d_ws;
    float* Xc     = (float*)p; p += (size_t)NODES * 128 * 4;
    float* A      = (float*)p; p += (size_t)NODES * 128 * 4;
    float* es     = (float*)p; p += (size_t)NODES * 4 * 4;
    float* ed     = (float*)p; p += (size_t)NODES * 4 * 4;
    float* Wc     = (float*)p; p += (size_t)W_TOTAL * 4;
    int*   deg    = (int*)p;   p += (size_t)NODES * 4;
    int*   rowptr = (int*)p;   p += (size_t)(NODES + 1) * 4;
    int*   col    = (int*)p;   p += (size_t)EPLUS * 4;
    int*   partial= (int*)p;   p += (size_t)NBLK * 4;
    int*   flags  = (int*)p;

    k_detect<<<1, 64, 0, stream>>>((const unsigned*)d_in[0], ei, flags);
    k_cvt_x<<<gs((long)NODES * 128), 256, 0, stream>>>(d_in[0], flags, Xc);
    k_cvt_w<<<gs(W_TOTAL), 256, 0, stream>>>(d_in[2], d_in[3], d_in[4], d_in[5],
                                             d_in[6], d_in[7], d_in[8], d_in[9],
                                             d_in[10], d_in[11], d_in[12], d_in[13],
                                             flags, Wc);

    hipMemsetAsync(deg, 0, (size_t)NODES * 4, stream);
    k_deg<<<gs(EPLUS), 256, 0, stream>>>(ei, flags, deg);
    k_scan_a<<<NBLK, 256, 0, stream>>>(deg, partial);
    k_scan_b<<<1, 256, 0, stream>>>(partial);
    k_scan_c<<<NBLK, 256, 0, stream>>>(deg, partial, rowptr);
    k_fill<<<gs(EPLUS), 256, 0, stream>>>(ei, flags, deg, col);

    const int ggrid = (NODES + 3) / 4;
    const int gemmgrid = NODES / 16;

    k_gemm128<<<gemmgrid, 256, 0, stream>>>(Xc, Wc + O_W1, Wc + O_AS1, Wc + O_AD1, A, es, ed);
    k_gather4<<<ggrid, 256, 0, stream>>>(rowptr, col, es, ed, A, Wc + O_B1, Xc);
    k_gemm128<<<gemmgrid, 256, 0, stream>>>(Xc, Wc + O_W2, Wc + O_AS2, Wc + O_AD2, A, es, ed);
    k_gather4<<<ggrid, 256, 0, stream>>>(rowptr, col, es, ed, A, Wc + O_B2, Xc);
    k_gemm16<<<gemmgrid, 256, 0, stream>>>(Xc, Wc + O_W3, Wc + O_AS3, Wc + O_AD3, A, es, ed);
    k_gather1<<<ggrid, 256, 0, stream>>>(rowptr, col, es, ed, A, Wc + O_B3, out);
}

// Round 9
// 463.663 us; speedup vs baseline: 1.9517x; 1.0664x over previous
//
#include <hip/hip_runtime.h>

#define NODES 50000
#define EDGES 800000
#define EPLUS (EDGES + NODES)
#define NBLK 196   // ceil(NODES/256)

// ---------- helpers ----------
__device__ __forceinline__ float ld_f(const void* p, int isbf, size_t i) {
    if (isbf) return __uint_as_float(((unsigned)((const unsigned short*)p)[i]) << 16);
    return ((const float*)p)[i];
}
__device__ __forceinline__ int ld_idx(const int* ei, int i64, int elem) {
    int v = i64 ? ei[(size_t)elem * 2] : ei[elem];   // little-endian low word
    v = v < 0 ? 0 : v;
    return v >= NODES ? NODES - 1 : v;               // defensive clamp
}

// ---------- dtype detection (1 thread) ----------
__global__ void k_detect(const unsigned* __restrict__ xw, const int* __restrict__ eiw,
                         int* __restrict__ flags) {
    if (threadIdx.x != 0 || blockIdx.x != 0) return;
    int sane = 0;
    for (int i = 0; i < 256; ++i) {
        unsigned lo = xw[i] & 0xFFFFu;
        int e = (int)((lo >> 7) & 0xFF);
        if (lo == 0u || (e >= 90 && e <= 140)) sane++;
    }
    flags[0] = (sane > 200) ? 1 : 0;
    int hiz = 0;
    for (int i = 0; i < 64; ++i)
        if (eiw[2 * i + 1] == 0) hiz++;
    flags[1] = (hiz > 48) ? 1 : 0;
}

// ---------- input normalization to fp32 ----------
__global__ void k_cvt_x(const void* __restrict__ x, const int* __restrict__ flags,
                        float* __restrict__ out) {
    int i = blockIdx.x * 256 + threadIdx.x;
    if (i < NODES * 128) out[i] = ld_f(x, flags[0], i);
}

__global__ void k_cvt_w(const void* w1, const void* as1, const void* ad1, const void* b1,
                        const void* w2, const void* as2, const void* ad2, const void* b2,
                        const void* w3, const void* as3, const void* ad3, const void* b3,
                        const int* __restrict__ flags, float* __restrict__ out) {
    int tid = blockIdx.x * 256 + threadIdx.x;
    const int sz[12] = {16384,128,128,128,16384,128,128,128,2048,16,16,16};
    const void* ps[12] = {w1,as1,ad1,b1,w2,as2,ad2,b2,w3,as3,ad3,b3};
    int isbf = flags[0];
    int off = 0;
#pragma unroll
    for (int s = 0; s < 12; ++s) {
        if (tid >= off && tid < off + sz[s]) out[tid] = ld_f(ps[s], isbf, tid - off);
        off += sz[s];
    }
}
#define O_W1 0
#define O_AS1 16384
#define O_AD1 16512
#define O_B1 16640
#define O_W2 16768
#define O_AS2 33152
#define O_AD2 33280
#define O_B2 33408
#define O_W3 33536
#define O_AS3 35584
#define O_AD3 35600
#define O_B3 35616
#define W_TOTAL 35632

// ---------- CSR build ----------
__global__ void k_deg(const int* __restrict__ ei, const int* __restrict__ flags,
                      int* __restrict__ deg) {
    int e = blockIdx.x * 256 + threadIdx.x;
    if (e >= EPLUS) return;
    int d = (e < EDGES) ? ld_idx(ei, flags[1], EDGES + e) : (e - EDGES);
    atomicAdd(&deg[d], 1);
}

__global__ void k_scan_a(const int* __restrict__ deg, int* __restrict__ partial) {
    __shared__ int ws[4];
    const int t = threadIdx.x;
    int idx = blockIdx.x * 256 + t;
    int v = (idx < NODES) ? deg[idx] : 0;
#pragma unroll
    for (int off = 1; off < 64; off <<= 1) v += __shfl_xor(v, off);
    if ((t & 63) == 0) ws[t >> 6] = v;
    __syncthreads();
    if (t == 0) partial[blockIdx.x] = ws[0] + ws[1] + ws[2] + ws[3];
}

__global__ void k_scan_b(int* __restrict__ partial) {
    __shared__ int s[256];
    const int t = threadIdx.x;
    int v = (t < NBLK) ? partial[t] : 0;
    s[t] = v;
    __syncthreads();
#pragma unroll
    for (int off = 1; off < 256; off <<= 1) {
        int add = (t >= off) ? s[t - off] : 0;
        __syncthreads();
        s[t] += add;
        __syncthreads();
    }
    if (t < NBLK) partial[t] = s[t] - v;   // exclusive
}

__global__ void k_scan_c(int* __restrict__ deg, const int* __restrict__ partial,
                         int* __restrict__ rowptr) {
    __shared__ int s[256];
    const int t = threadIdx.x;
    const int idx = blockIdx.x * 256 + t;
    int v = (idx < NODES) ? deg[idx] : 0;
    s[t] = v;
    __syncthreads();
#pragma unroll
    for (int off = 1; off < 256; off <<= 1) {
        int add = (t >= off) ? s[t - off] : 0;
        __syncthreads();
        s[t] += add;
        __syncthreads();
    }
    int ex = partial[blockIdx.x] + s[t] - v;
    if (idx < NODES) {
        rowptr[idx] = ex;
        deg[idx] = ex;                     // becomes cursor
    } else if (idx == NODES) {
        rowptr[NODES] = ex;
    }
}

__global__ void k_fill(const int* __restrict__ ei, const int* __restrict__ flags,
                       int* __restrict__ cursor, int* __restrict__ col) {
    int e = blockIdx.x * 256 + threadIdx.x;
    if (e >= EPLUS) return;
    int s, d;
    if (e < EDGES) {
        int i64 = flags[1];
        s = ld_idx(ei, i64, e);
        d = ld_idx(ei, i64, EDGES + e);
    } else s = d = e - EDGES;
    col[atomicAdd(&cursor[d], 1)] = s;
}

// ---------- GEMM 128->128 + scores, register-tiled 8x8 ----------
// 391 blocks x 256 thr; tile 128 rows x 128 cols, BK=32.
// thread: tx=t&15 (cols tx*4..+3 and 64+tx*4..+3), ty=t>>4 (rows ty*8..+7)
__global__ __launch_bounds__(256, 2) void k_gemm128(
        const float* __restrict__ in, const float* __restrict__ W,
        const float* __restrict__ a_s, const float* __restrict__ a_d,
        float* __restrict__ hout, float* __restrict__ es, float* __restrict__ ed) {
    __shared__ float Xl[32][132];       // transposed [k][row], pad 132
    __shared__ float Wl[32][128];       // [k][col]
    const int t = threadIdx.x;
    const int rowBase = blockIdx.x * 128;
    const int tx = t & 15, ty = t >> 4;
    const int cA = tx * 4, cB = 64 + tx * 4;

    float acc[8][8];
#pragma unroll
    for (int r = 0; r < 8; ++r)
#pragma unroll
        for (int j = 0; j < 8; ++j) acc[r][j] = 0.f;

    for (int k0 = 0; k0 < 128; k0 += 32) {
        __syncthreads();
        // stage W tile [32][128]
        const float4* Wg = (const float4*)(W + k0 * 128);
        float4* Wl4 = (float4*)&Wl[0][0];
#pragma unroll
        for (int j = 0; j < 4; ++j) Wl4[t + 256 * j] = Wg[t + 256 * j];
        // stage X tile transposed: rows rowBase..+127, k0..k0+31
#pragma unroll
        for (int j = 0; j < 4; ++j) {
            int f = t + 256 * j;
            int r = f >> 3;
            int kk = (f & 7) * 4;
            int gr = rowBase + r;
            if (gr >= NODES) gr = NODES - 1;
            float4 v = *(const float4*)(in + (size_t)gr * 128 + k0 + kk);
            Xl[kk][r] = v.x; Xl[kk + 1][r] = v.y; Xl[kk + 2][r] = v.z; Xl[kk + 3][r] = v.w;
        }
        __syncthreads();
#pragma unroll 4
        for (int k = 0; k < 32; ++k) {
            const float4 xa = *(const float4*)&Xl[k][ty * 8];
            const float4 xb = *(const float4*)&Xl[k][ty * 8 + 4];
            const float4 wa = *(const float4*)&Wl[k][cA];
            const float4 wb = *(const float4*)&Wl[k][cB];
            const float xs[8] = {xa.x, xa.y, xa.z, xa.w, xb.x, xb.y, xb.z, xb.w};
            const float ws[8] = {wa.x, wa.y, wa.z, wa.w, wb.x, wb.y, wb.z, wb.w};
#pragma unroll
            for (int r = 0; r < 8; ++r)
#pragma unroll
                for (int j = 0; j < 8; ++j)
                    acc[r][j] += xs[r] * ws[j];
        }
    }

    // epilogue: store h + fused es/ed
    float asA[4], asB[4], adA[4], adB[4];
#pragma unroll
    for (int j = 0; j < 4; ++j) {
        asA[j] = a_s[cA + j]; asB[j] = a_s[cB + j];
        adA[j] = a_d[cA + j]; adB[j] = a_d[cB + j];
    }
    const int hA = tx >> 3;             // 0/1; B-group head = 2+hA
#pragma unroll
    for (int r = 0; r < 8; ++r) {
        const int row = rowBase + ty * 8 + r;
        const bool ok = row < NODES;
        if (ok) {
            *(float4*)&hout[(size_t)row * 128 + cA] =
                make_float4(acc[r][0], acc[r][1], acc[r][2], acc[r][3]);
            *(float4*)&hout[(size_t)row * 128 + cB] =
                make_float4(acc[r][4], acc[r][5], acc[r][6], acc[r][7]);
        }
        float seA = acc[r][0]*asA[0] + acc[r][1]*asA[1] + acc[r][2]*asA[2] + acc[r][3]*asA[3];
        float seB = acc[r][4]*asB[0] + acc[r][5]*asB[1] + acc[r][6]*asB[2] + acc[r][7]*asB[3];
        float sdA = acc[r][0]*adA[0] + acc[r][1]*adA[1] + acc[r][2]*adA[2] + acc[r][3]*adA[3];
        float sdB = acc[r][4]*adB[0] + acc[r][5]*adB[1] + acc[r][6]*adB[2] + acc[r][7]*adB[3];
#pragma unroll
        for (int off = 1; off < 8; off <<= 1) {
            seA += __shfl_xor(seA, off);
            seB += __shfl_xor(seB, off);
            sdA += __shfl_xor(sdA, off);
            sdB += __shfl_xor(sdB, off);
        }
        if (ok && (tx & 7) == 0) {
            es[row * 4 + hA]     = seA;
            es[row * 4 + 2 + hA] = seB;
            ed[row * 4 + hA]     = sdA;
            ed[row * 4 + 2 + hA] = sdB;
        }
    }
}

// ---------- GEMM 128->16 + scores (H=1), register-tiled 2x4 ----------
// 391 blocks x 256 thr; tile 128 rows x 16 cols, BK=32.
// thread: tx=t&3 (cols tx*4..+3), ty=t>>2 (rows ty*2..+1)
__global__ __launch_bounds__(256, 2) void k_gemm16(
        const float* __restrict__ in, const float* __restrict__ W,
        const float* __restrict__ a_s, const float* __restrict__ a_d,
        float* __restrict__ hout, float* __restrict__ es, float* __restrict__ ed) {
    __shared__ float Xl[32][132];
    __shared__ float Wl[128 * 16];      // full W, [k][col]
    const int t = threadIdx.x;
    const int rowBase = blockIdx.x * 128;
    const int tx = t & 3, ty = t >> 2;

    // stage full W
    ((float4*)Wl)[t] = ((const float4*)W)[t];
    ((float4*)Wl)[t + 256] = ((const float4*)W)[t + 256];

    float acc[2][4];
#pragma unroll
    for (int r = 0; r < 2; ++r)
#pragma unroll
        for (int j = 0; j < 4; ++j) acc[r][j] = 0.f;

    for (int k0 = 0; k0 < 128; k0 += 32) {
        __syncthreads();
#pragma unroll
        for (int j = 0; j < 4; ++j) {
            int f = t + 256 * j;
            int r = f >> 3;
            int kk = (f & 7) * 4;
            int gr = rowBase + r;
            if (gr >= NODES) gr = NODES - 1;
            float4 v = *(const float4*)(in + (size_t)gr * 128 + k0 + kk);
            Xl[kk][r] = v.x; Xl[kk + 1][r] = v.y; Xl[kk + 2][r] = v.z; Xl[kk + 3][r] = v.w;
        }
        __syncthreads();
#pragma unroll 4
        for (int k = 0; k < 32; ++k) {
            const float2 xv = *(const float2*)&Xl[k][ty * 2];
            const float4 wv = *(const float4*)&Wl[(k0 + k) * 16 + tx * 4];
            acc[0][0] += xv.x * wv.x; acc[0][1] += xv.x * wv.y;
            acc[0][2] += xv.x * wv.z; acc[0][3] += xv.x * wv.w;
            acc[1][0] += xv.y * wv.x; acc[1][1] += xv.y * wv.y;
            acc[1][2] += xv.y * wv.z; acc[1][3] += xv.y * wv.w;
        }
    }

    const float4 asv = *(const float4*)&a_s[tx * 4];
    const float4 adv = *(const float4*)&a_d[tx * 4];
#pragma unroll
    for (int r = 0; r < 2; ++r) {
        const int row = rowBase + ty * 2 + r;
        const bool ok = row < NODES;
        if (ok)
            *(float4*)&hout[(size_t)row * 16 + tx * 4] =
                make_float4(acc[r][0], acc[r][1], acc[r][2], acc[r][3]);
        float se = acc[r][0]*asv.x + acc[r][1]*asv.y + acc[r][2]*asv.z + acc[r][3]*asv.w;
        float sd = acc[r][0]*adv.x + acc[r][1]*adv.y + acc[r][2]*adv.z + acc[r][3]*adv.w;
#pragma unroll
        for (int off = 1; off < 4; off <<= 1) {
            se += __shfl_xor(se, off);
            sd += __shfl_xor(sd, off);
        }
        if (ok && tx == 0) { es[row] = se; ed[row] = sd; }
    }
}

// ---------- gather softmax + aggregate, H=4, C=32 ----------
__global__ void k_gather4(const int* __restrict__ rowptr, const int* __restrict__ col,
                          const float* __restrict__ es, const float* __restrict__ ed,
                          const float* __restrict__ hfeat, const float* __restrict__ bias,
                          float* __restrict__ outf) {
    const int nd = blockIdx.x * 4 + (threadIdx.x >> 6);
    if (nd >= NODES) return;
    const int lane = threadIdx.x & 63;
    const int start = rowptr[nd], deg = rowptr[nd + 1] - start;

    float ed4[4], m[4], sm[4];
#pragma unroll
    for (int h = 0; h < 4; ++h) { ed4[h] = ed[nd * 4 + h]; m[h] = -1e30f; sm[h] = 0.f; }

    for (int e = lane; e < deg; e += 64) {
        int src = col[start + e];
#pragma unroll
        for (int h = 0; h < 4; ++h) {
            float v = es[src * 4 + h] + ed4[h];
            v = v > 0.f ? v : 0.2f * v;
            m[h] = fmaxf(m[h], v);
        }
    }
#pragma unroll
    for (int h = 0; h < 4; ++h)
        for (int off = 1; off < 64; off <<= 1)
            m[h] = fmaxf(m[h], __shfl_xor(m[h], off));

    for (int e = lane; e < deg; e += 64) {
        int src = col[start + e];
#pragma unroll
        for (int h = 0; h < 4; ++h) {
            float v = es[src * 4 + h] + ed4[h];
            v = v > 0.f ? v : 0.2f * v;
            sm[h] += __expf(v - m[h]);
        }
    }
#pragma unroll
    for (int h = 0; h < 4; ++h) {
        for (int off = 1; off < 64; off <<= 1)
            sm[h] += __shfl_xor(sm[h], off);
        sm[h] = 1.f / (sm[h] + 1e-16f);
    }

    const int esub = lane >> 5;
    const int cl = lane & 31;
    const int myh = cl >> 3;
    const float mh = m[myh], smh = sm[myh], edh = ed4[myh];
    const float4* __restrict__ h4 = (const float4*)hfeat;
    float ax = 0.f, ay = 0.f, az = 0.f, aw = 0.f;

    int e = esub;
    for (; e + 2 < deg; e += 4) {
        int s0 = col[start + e];
        int s1 = col[start + e + 2];
        float4 f0 = h4[(size_t)s0 * 32 + cl];
        float4 f1 = h4[(size_t)s1 * 32 + cl];
        float v0 = es[s0 * 4 + myh] + edh; v0 = v0 > 0.f ? v0 : 0.2f * v0;
        float v1 = es[s1 * 4 + myh] + edh; v1 = v1 > 0.f ? v1 : 0.2f * v1;
        float al0 = __expf(v0 - mh) * smh;
        float al1 = __expf(v1 - mh) * smh;
        ax += al0 * f0.x + al1 * f1.x;
        ay += al0 * f0.y + al1 * f1.y;
        az += al0 * f0.z + al1 * f1.z;
        aw += al0 * f0.w + al1 * f1.w;
    }
    for (; e < deg; e += 2) {
        int s0 = col[start + e];
        float4 f0 = h4[(size_t)s0 * 32 + cl];
        float v0 = es[s0 * 4 + myh] + edh; v0 = v0 > 0.f ? v0 : 0.2f * v0;
        float al0 = __expf(v0 - mh) * smh;
        ax += al0 * f0.x;
        ay += al0 * f0.y;
        az += al0 * f0.z;
        aw += al0 * f0.w;
    }
    ax += __shfl_xor(ax, 32);
    ay += __shfl_xor(ay, 32);
    az += __shfl_xor(az, 32);
    aw += __shfl_xor(aw, 32);

    if (esub == 0) {
        float4 b = ((const float4*)bias)[cl];
        ax += b.x; ay += b.y; az += b.z; aw += b.w;
        ax = ax > 0.f ? ax : 0.f;
        ay = ay > 0.f ? ay : 0.f;
        az = az > 0.f ? az : 0.f;
        aw = aw > 0.f ? aw : 0.f;
        ((float4*)outf)[(size_t)nd * 32 + cl] = make_float4(ax, ay, az, aw);
    }
}

// ---------- gather H=1, C=16, writes fp32 d_out ----------
__global__ void k_gather1(const int* __restrict__ rowptr, const int* __restrict__ col,
                          const float* __restrict__ es, const float* __restrict__ ed,
                          const float* __restrict__ hfeat, const float* __restrict__ bias,
                          float* __restrict__ outf) {
    const int nd = blockIdx.x * 4 + (threadIdx.x >> 6);
    if (nd >= NODES) return;
    const int lane = threadIdx.x & 63;
    const int start = rowptr[nd], deg = rowptr[nd + 1] - start;

    const float edv = ed[nd];
    float m = -1e30f, sm = 0.f;
    for (int e = lane; e < deg; e += 64) {
        float v = es[col[start + e]] + edv;
        v = v > 0.f ? v : 0.2f * v;
        m = fmaxf(m, v);
    }
    for (int off = 1; off < 64; off <<= 1) m = fmaxf(m, __shfl_xor(m, off));
    for (int e = lane; e < deg; e += 64) {
        float v = es[col[start + e]] + edv;
        v = v > 0.f ? v : 0.2f * v;
        sm += __expf(v - m);
    }
    for (int off = 1; off < 64; off <<= 1) sm += __shfl_xor(sm, off);
    sm = 1.f / (sm + 1e-16f);

    const int esub = lane >> 4;
    const int c = lane & 15;
    float acc = 0.f;
    int e = esub;
    for (; e + 4 < deg; e += 8) {
        int s0 = col[start + e];
        int s1 = col[start + e + 4];
        float f0 = hfeat[(size_t)s0 * 16 + c];
        float f1 = hfeat[(size_t)s1 * 16 + c];
        float v0 = es[s0] + edv; v0 = v0 > 0.f ? v0 : 0.2f * v0;
        float v1 = es[s1] + edv; v1 = v1 > 0.f ? v1 : 0.2f * v1;
        acc += __expf(v0 - m) * sm * f0 + __expf(v1 - m) * sm * f1;
    }
    for (; e < deg; e += 4) {
        int s0 = col[start + e];
        float f0 = hfeat[(size_t)s0 * 16 + c];
        float v0 = es[s0] + edv; v0 = v0 > 0.f ? v0 : 0.2f * v0;
        acc += __expf(v0 - m) * sm * f0;
    }
    acc += __shfl_xor(acc, 32);
    acc += __shfl_xor(acc, 16);
    if (lane < 16)
        outf[(size_t)nd * 16 + lane] = acc + bias[lane];
}

static inline int gs(long n) { return (int)((n + 255) / 256); }

extern "C" void kernel_launch(void* const* d_in, const int* in_sizes, int n_in,
                              void* d_out, int out_size, void* d_ws, size_t ws_size,
                              hipStream_t stream) {
    const int* ei = (const int*)d_in[1];
    float* out = (float*)d_out;

    char* p = (char*)d_ws;
    float* Xc     = (float*)p; p += (size_t)NODES * 128 * 4;
    float* A      = (float*)p; p += (size_t)NODES * 128 * 4;
    float* es     = (float*)p; p += (size_t)NODES * 4 * 4;
    float* ed     = (float*)p; p += (size_t)NODES * 4 * 4;
    float* Wc     = (float*)p; p += (size_t)W_TOTAL * 4;
    int*   deg    = (int*)p;   p += (size_t)NODES * 4;
    int*   rowptr = (int*)p;   p += (size_t)(NODES + 1) * 4;
    int*   col    = (int*)p;   p += (size_t)EPLUS * 4;
    int*   partial= (int*)p;   p += (size_t)NBLK * 4;
    int*   flags  = (int*)p;

    k_detect<<<1, 64, 0, stream>>>((const unsigned*)d_in[0], ei, flags);
    k_cvt_x<<<gs((long)NODES * 128), 256, 0, stream>>>(d_in[0], flags, Xc);
    k_cvt_w<<<gs(W_TOTAL), 256, 0, stream>>>(d_in[2], d_in[3], d_in[4], d_in[5],
                                             d_in[6], d_in[7], d_in[8], d_in[9],
                                             d_in[10], d_in[11], d_in[12], d_in[13],
                                             flags, Wc);

    hipMemsetAsync(deg, 0, (size_t)NODES * 4, stream);
    k_deg<<<gs(EPLUS), 256, 0, stream>>>(ei, flags, deg);
    k_scan_a<<<NBLK, 256, 0, stream>>>(deg, partial);
    k_scan_b<<<1, 256, 0, stream>>>(partial);
    k_scan_c<<<NBLK, 256, 0, stream>>>(deg, partial, rowptr);
    k_fill<<<gs(EPLUS), 256, 0, stream>>>(ei, flags, deg, col);

    const int ggrid = (NODES + 3) / 4;
    const int gemmgrid = (NODES + 127) / 128;   // 391

    k_gemm128<<<gemmgrid, 256, 0, stream>>>(Xc, Wc + O_W1, Wc + O_AS1, Wc + O_AD1, A, es, ed);
    k_gather4<<<ggrid, 256, 0, stream>>>(rowptr, col, es, ed, A, Wc + O_B1, Xc);
    k_gemm128<<<gemmgrid, 256, 0, stream>>>(Xc, Wc + O_W2, Wc + O_AS2, Wc + O_AD2, A, es, ed);
    k_gather4<<<ggrid, 256, 0, stream>>>(rowptr, col, es, ed, A, Wc + O_B2, Xc);
    k_gemm16<<<gemmgrid, 256, 0, stream>>>(Xc, Wc + O_W3, Wc + O_AS3, Wc + O_AD3, A, es, ed);
    k_gather1<<<ggrid, 256, 0, stream>>>(rowptr, col, es, ed, A, Wc + O_B3, out);
}

// Round 10
// 412.133 us; speedup vs baseline: 2.1957x; 1.1250x over previous
//
#include <hip/hip_runtime.h>

#define NODES 50000
#define EDGES 800000
#define EPLUS (EDGES + NODES)
#define NBLK 196   // ceil(NODES/256)

// ---------- helpers ----------
__device__ __forceinline__ float ld_f(const void* p, int isbf, size_t i) {
    if (isbf) return __uint_as_float(((unsigned)((const unsigned short*)p)[i]) << 16);
    return ((const float*)p)[i];
}
__device__ __forceinline__ int ld_idx(const int* ei, int i64, int elem) {
    int v = i64 ? ei[(size_t)elem * 2] : ei[elem];
    v = v < 0 ? 0 : v;
    return v >= NODES ? NODES - 1 : v;
}
__device__ __forceinline__ unsigned short f2bf(float f) {
    unsigned u = __float_as_uint(f);
    u = u + 0x7FFFu + ((u >> 16) & 1u);   // RNE
    return (unsigned short)(u >> 16);
}
__device__ __forceinline__ unsigned pack2bf(float a, float b) {
    return (unsigned)f2bf(a) | ((unsigned)f2bf(b) << 16);
}
__device__ __forceinline__ float bflo(unsigned u) { return __uint_as_float(u << 16); }
__device__ __forceinline__ float bfhi(unsigned u) { return __uint_as_float(u & 0xFFFF0000u); }

// ---------- dtype detection ----------
__global__ void k_detect(const unsigned* __restrict__ xw, const int* __restrict__ eiw,
                         int* __restrict__ flags) {
    if (threadIdx.x != 0 || blockIdx.x != 0) return;
    int sane = 0;
    for (int i = 0; i < 256; ++i) {
        unsigned lo = xw[i] & 0xFFFFu;
        int e = (int)((lo >> 7) & 0xFF);
        if (lo == 0u || (e >= 90 && e <= 140)) sane++;
    }
    flags[0] = (sane > 200) ? 1 : 0;
    int hiz = 0;
    for (int i = 0; i < 64; ++i)
        if (eiw[2 * i + 1] == 0) hiz++;
    flags[1] = (hiz > 48) ? 1 : 0;
}

// ---------- input normalization ----------
__global__ void k_cvt_x(const void* __restrict__ x, const int* __restrict__ flags,
                        float* __restrict__ out) {
    int i = blockIdx.x * 256 + threadIdx.x;
    if (i < NODES * 128) out[i] = ld_f(x, flags[0], i);
}

__global__ void k_cvt_w(const void* w1, const void* as1, const void* ad1, const void* b1,
                        const void* w2, const void* as2, const void* ad2, const void* b2,
                        const void* w3, const void* as3, const void* ad3, const void* b3,
                        const int* __restrict__ flags, float* __restrict__ out) {
    int tid = blockIdx.x * 256 + threadIdx.x;
    const int sz[12] = {16384,128,128,128,16384,128,128,128,2048,16,16,16};
    const void* ps[12] = {w1,as1,ad1,b1,w2,as2,ad2,b2,w3,as3,ad3,b3};
    int isbf = flags[0];
    int off = 0;
#pragma unroll
    for (int s = 0; s < 12; ++s) {
        if (tid >= off && tid < off + sz[s]) out[tid] = ld_f(ps[s], isbf, tid - off);
        off += sz[s];
    }
}
#define O_W1 0
#define O_AS1 16384
#define O_AD1 16512
#define O_B1 16640
#define O_W2 16768
#define O_AS2 33152
#define O_AD2 33280
#define O_B2 33408
#define O_W3 33536
#define O_AS3 35584
#define O_AD3 35600
#define O_B3 35616
#define W_TOTAL 35632

// ---------- CSR build ----------
__global__ void k_deg(const int* __restrict__ ei, const int* __restrict__ flags,
                      int* __restrict__ deg) {
    int e = blockIdx.x * 256 + threadIdx.x;
    if (e >= EPLUS) return;
    int d = (e < EDGES) ? ld_idx(ei, flags[1], EDGES + e) : (e - EDGES);
    atomicAdd(&deg[d], 1);
}

__global__ void k_scan_a(const int* __restrict__ deg, int* __restrict__ partial) {
    __shared__ int ws[4];
    const int t = threadIdx.x;
    int idx = blockIdx.x * 256 + t;
    int v = (idx < NODES) ? deg[idx] : 0;
#pragma unroll
    for (int off = 1; off < 64; off <<= 1) v += __shfl_xor(v, off);
    if ((t & 63) == 0) ws[t >> 6] = v;
    __syncthreads();
    if (t == 0) partial[blockIdx.x] = ws[0] + ws[1] + ws[2] + ws[3];
}

__global__ void k_scan_b(int* __restrict__ partial) {
    __shared__ int s[256];
    const int t = threadIdx.x;
    int v = (t < NBLK) ? partial[t] : 0;
    s[t] = v;
    __syncthreads();
#pragma unroll
    for (int off = 1; off < 256; off <<= 1) {
        int add = (t >= off) ? s[t - off] : 0;
        __syncthreads();
        s[t] += add;
        __syncthreads();
    }
    if (t < NBLK) partial[t] = s[t] - v;
}

__global__ void k_scan_c(int* __restrict__ deg, const int* __restrict__ partial,
                         int* __restrict__ rowptr) {
    __shared__ int s[256];
    const int t = threadIdx.x;
    const int idx = blockIdx.x * 256 + t;
    int v = (idx < NODES) ? deg[idx] : 0;
    s[t] = v;
    __syncthreads();
#pragma unroll
    for (int off = 1; off < 256; off <<= 1) {
        int add = (t >= off) ? s[t - off] : 0;
        __syncthreads();
        s[t] += add;
        __syncthreads();
    }
    int ex = partial[blockIdx.x] + s[t] - v;
    if (idx < NODES) {
        rowptr[idx] = ex;
        deg[idx] = ex;
    } else if (idx == NODES) {
        rowptr[NODES] = ex;
    }
}

__global__ void k_fill(const int* __restrict__ ei, const int* __restrict__ flags,
                       int* __restrict__ cursor, int* __restrict__ col) {
    int e = blockIdx.x * 256 + threadIdx.x;
    if (e >= EPLUS) return;
    int s, d;
    if (e < EDGES) {
        int i64 = flags[1];
        s = ld_idx(ei, i64, e);
        d = ld_idx(ei, i64, EDGES + e);
    } else s = d = e - EDGES;
    col[atomicAdd(&cursor[d], 1)] = s;
}

// ---------- GEMM 128->128 + scores, 8x8 register tile; h stored bf16 ----------
__global__ __launch_bounds__(256, 2) void k_gemm128(
        const float* __restrict__ in, const float* __restrict__ W,
        const float* __restrict__ a_s, const float* __restrict__ a_d,
        unsigned short* __restrict__ hout, float* __restrict__ es, float* __restrict__ ed) {
    __shared__ float Xl[32][132];
    __shared__ float Wl[32][128];
    const int t = threadIdx.x;
    const int rowBase = blockIdx.x * 128;
    const int tx = t & 15, ty = t >> 4;
    const int cA = tx * 4, cB = 64 + tx * 4;

    float acc[8][8];
#pragma unroll
    for (int r = 0; r < 8; ++r)
#pragma unroll
        for (int j = 0; j < 8; ++j) acc[r][j] = 0.f;

    for (int k0 = 0; k0 < 128; k0 += 32) {
        __syncthreads();
        const float4* Wg = (const float4*)(W + k0 * 128);
        float4* Wl4 = (float4*)&Wl[0][0];
#pragma unroll
        for (int j = 0; j < 4; ++j) Wl4[t + 256 * j] = Wg[t + 256 * j];
#pragma unroll
        for (int j = 0; j < 4; ++j) {
            int f = t + 256 * j;
            int r = f >> 3;
            int kk = (f & 7) * 4;
            int gr = rowBase + r;
            if (gr >= NODES) gr = NODES - 1;
            float4 v = *(const float4*)(in + (size_t)gr * 128 + k0 + kk);
            Xl[kk][r] = v.x; Xl[kk + 1][r] = v.y; Xl[kk + 2][r] = v.z; Xl[kk + 3][r] = v.w;
        }
        __syncthreads();
#pragma unroll 4
        for (int k = 0; k < 32; ++k) {
            const float4 xa = *(const float4*)&Xl[k][ty * 8];
            const float4 xb = *(const float4*)&Xl[k][ty * 8 + 4];
            const float4 wa = *(const float4*)&Wl[k][cA];
            const float4 wb = *(const float4*)&Wl[k][cB];
            const float xs[8] = {xa.x, xa.y, xa.z, xa.w, xb.x, xb.y, xb.z, xb.w};
            const float ws[8] = {wa.x, wa.y, wa.z, wa.w, wb.x, wb.y, wb.z, wb.w};
#pragma unroll
            for (int r = 0; r < 8; ++r)
#pragma unroll
                for (int j = 0; j < 8; ++j)
                    acc[r][j] += xs[r] * ws[j];
        }
    }

    float asA[4], asB[4], adA[4], adB[4];
#pragma unroll
    for (int j = 0; j < 4; ++j) {
        asA[j] = a_s[cA + j]; asB[j] = a_s[cB + j];
        adA[j] = a_d[cA + j]; adB[j] = a_d[cB + j];
    }
    const int hA = tx >> 3;
#pragma unroll
    for (int r = 0; r < 8; ++r) {
        const int row = rowBase + ty * 8 + r;
        const bool ok = row < NODES;
        if (ok) {
            uint2 pA = {pack2bf(acc[r][0], acc[r][1]), pack2bf(acc[r][2], acc[r][3])};
            uint2 pB = {pack2bf(acc[r][4], acc[r][5]), pack2bf(acc[r][6], acc[r][7])};
            *(uint2*)&hout[(size_t)row * 128 + cA] = pA;
            *(uint2*)&hout[(size_t)row * 128 + cB] = pB;
        }
        float seA = acc[r][0]*asA[0] + acc[r][1]*asA[1] + acc[r][2]*asA[2] + acc[r][3]*asA[3];
        float seB = acc[r][4]*asB[0] + acc[r][5]*asB[1] + acc[r][6]*asB[2] + acc[r][7]*asB[3];
        float sdA = acc[r][0]*adA[0] + acc[r][1]*adA[1] + acc[r][2]*adA[2] + acc[r][3]*adA[3];
        float sdB = acc[r][4]*adB[0] + acc[r][5]*adB[1] + acc[r][6]*adB[2] + acc[r][7]*adB[3];
#pragma unroll
        for (int off = 1; off < 8; off <<= 1) {
            seA += __shfl_xor(seA, off);
            seB += __shfl_xor(seB, off);
            sdA += __shfl_xor(sdA, off);
            sdB += __shfl_xor(sdB, off);
        }
        if (ok && (tx & 7) == 0) {
            es[row * 4 + hA]     = seA;
            es[row * 4 + 2 + hA] = seB;
            ed[row * 4 + hA]     = sdA;
            ed[row * 4 + 2 + hA] = sdB;
        }
    }
}

// ---------- GEMM 128->16 + scores (H=1); h stored bf16 ----------
__global__ __launch_bounds__(256, 2) void k_gemm16(
        const float* __restrict__ in, const float* __restrict__ W,
        const float* __restrict__ a_s, const float* __restrict__ a_d,
        unsigned short* __restrict__ hout, float* __restrict__ es, float* __restrict__ ed) {
    __shared__ float Xl[32][132];
    __shared__ float Wl[128 * 16];
    const int t = threadIdx.x;
    const int rowBase = blockIdx.x * 128;
    const int tx = t & 3, ty = t >> 2;

    ((float4*)Wl)[t] = ((const float4*)W)[t];
    ((float4*)Wl)[t + 256] = ((const float4*)W)[t + 256];

    float acc[2][4];
#pragma unroll
    for (int r = 0; r < 2; ++r)
#pragma unroll
        for (int j = 0; j < 4; ++j) acc[r][j] = 0.f;

    for (int k0 = 0; k0 < 128; k0 += 32) {
        __syncthreads();
#pragma unroll
        for (int j = 0; j < 4; ++j) {
            int f = t + 256 * j;
            int r = f >> 3;
            int kk = (f & 7) * 4;
            int gr = rowBase + r;
            if (gr >= NODES) gr = NODES - 1;
            float4 v = *(const float4*)(in + (size_t)gr * 128 + k0 + kk);
            Xl[kk][r] = v.x; Xl[kk + 1][r] = v.y; Xl[kk + 2][r] = v.z; Xl[kk + 3][r] = v.w;
        }
        __syncthreads();
#pragma unroll 4
        for (int k = 0; k < 32; ++k) {
            const float2 xv = *(const float2*)&Xl[k][ty * 2];
            const float4 wv = *(const float4*)&Wl[(k0 + k) * 16 + tx * 4];
            acc[0][0] += xv.x * wv.x; acc[0][1] += xv.x * wv.y;
            acc[0][2] += xv.x * wv.z; acc[0][3] += xv.x * wv.w;
            acc[1][0] += xv.y * wv.x; acc[1][1] += xv.y * wv.y;
            acc[1][2] += xv.y * wv.z; acc[1][3] += xv.y * wv.w;
        }
    }

    const float4 asv = *(const float4*)&a_s[tx * 4];
    const float4 adv = *(const float4*)&a_d[tx * 4];
#pragma unroll
    for (int r = 0; r < 2; ++r) {
        const int row = rowBase + ty * 2 + r;
        const bool ok = row < NODES;
        if (ok) {
            uint2 pk = {pack2bf(acc[r][0], acc[r][1]), pack2bf(acc[r][2], acc[r][3])};
            *(uint2*)&hout[(size_t)row * 16 + tx * 4] = pk;
        }
        float se = acc[r][0]*asv.x + acc[r][1]*asv.y + acc[r][2]*asv.z + acc[r][3]*asv.w;
        float sd = acc[r][0]*adv.x + acc[r][1]*adv.y + acc[r][2]*adv.z + acc[r][3]*adv.w;
#pragma unroll
        for (int off = 1; off < 4; off <<= 1) {
            se += __shfl_xor(se, off);
            sd += __shfl_xor(sd, off);
        }
        if (ok && tx == 0) { es[row] = se; ed[row] = sd; }
    }
}

// ---------- gather H=4: softmax + aggregate; h is bf16 ----------
// pass3: 4 edge-subgroups x 16 lanes, lane owns 8 channels (one uint4 of bf16)
__global__ void k_gather4(const int* __restrict__ rowptr, const int* __restrict__ col,
                          const float* __restrict__ es, const float* __restrict__ ed,
                          const unsigned short* __restrict__ hfeat,
                          const float* __restrict__ bias, float* __restrict__ outf) {
    const int nd = blockIdx.x * 4 + (threadIdx.x >> 6);
    if (nd >= NODES) return;
    const int lane = threadIdx.x & 63;
    const int start = rowptr[nd], deg = rowptr[nd + 1] - start;

    float ed4[4], m[4], sm[4];
#pragma unroll
    for (int h = 0; h < 4; ++h) { ed4[h] = ed[nd * 4 + h]; m[h] = -1e30f; sm[h] = 0.f; }

    for (int e = lane; e < deg; e += 64) {
        int src = col[start + e];
#pragma unroll
        for (int h = 0; h < 4; ++h) {
            float v = es[src * 4 + h] + ed4[h];
            v = v > 0.f ? v : 0.2f * v;
            m[h] = fmaxf(m[h], v);
        }
    }
#pragma unroll
    for (int h = 0; h < 4; ++h)
        for (int off = 1; off < 64; off <<= 1)
            m[h] = fmaxf(m[h], __shfl_xor(m[h], off));

    for (int e = lane; e < deg; e += 64) {
        int src = col[start + e];
#pragma unroll
        for (int h = 0; h < 4; ++h) {
            float v = es[src * 4 + h] + ed4[h];
            v = v > 0.f ? v : 0.2f * v;
            sm[h] += __expf(v - m[h]);
        }
    }
#pragma unroll
    for (int h = 0; h < 4; ++h) {
        for (int off = 1; off < 64; off <<= 1)
            sm[h] += __shfl_xor(sm[h], off);
        sm[h] = 1.f / (sm[h] + 1e-16f);
    }

    const int esub = lane >> 4;          // 0..3
    const int c = lane & 15;             // lane owns channels 8c..8c+7
    const int myh = c >> 2;
    const float mh = m[myh], smh = sm[myh], edh = ed4[myh];
    const uint4* __restrict__ h4 = (const uint4*)hfeat;   // bf16 row = 16 uint4
    float a[8] = {0.f,0.f,0.f,0.f,0.f,0.f,0.f,0.f};

    int e = esub;
    for (; e + 4 < deg; e += 8) {
        int s0 = col[start + e];
        int s1 = col[start + e + 4];
        uint4 u0 = h4[(size_t)s0 * 16 + c];
        uint4 u1 = h4[(size_t)s1 * 16 + c];
        float v0 = es[s0 * 4 + myh] + edh; v0 = v0 > 0.f ? v0 : 0.2f * v0;
        float v1 = es[s1 * 4 + myh] + edh; v1 = v1 > 0.f ? v1 : 0.2f * v1;
        float al0 = __expf(v0 - mh) * smh;
        float al1 = __expf(v1 - mh) * smh;
        a[0] += al0 * bflo(u0.x) + al1 * bflo(u1.x);
        a[1] += al0 * bfhi(u0.x) + al1 * bfhi(u1.x);
        a[2] += al0 * bflo(u0.y) + al1 * bflo(u1.y);
        a[3] += al0 * bfhi(u0.y) + al1 * bfhi(u1.y);
        a[4] += al0 * bflo(u0.z) + al1 * bflo(u1.z);
        a[5] += al0 * bfhi(u0.z) + al1 * bfhi(u1.z);
        a[6] += al0 * bflo(u0.w) + al1 * bflo(u1.w);
        a[7] += al0 * bfhi(u0.w) + al1 * bfhi(u1.w);
    }
    for (; e < deg; e += 4) {
        int s0 = col[start + e];
        uint4 u0 = h4[(size_t)s0 * 16 + c];
        float v0 = es[s0 * 4 + myh] + edh; v0 = v0 > 0.f ? v0 : 0.2f * v0;
        float al0 = __expf(v0 - mh) * smh;
        a[0] += al0 * bflo(u0.x);
        a[1] += al0 * bfhi(u0.x);
        a[2] += al0 * bflo(u0.y);
        a[3] += al0 * bfhi(u0.y);
        a[4] += al0 * bflo(u0.z);
        a[5] += al0 * bfhi(u0.z);
        a[6] += al0 * bflo(u0.w);
        a[7] += al0 * bfhi(u0.w);
    }
#pragma unroll
    for (int j = 0; j < 8; ++j) {
        a[j] += __shfl_xor(a[j], 16);
        a[j] += __shfl_xor(a[j], 32);
    }

    if (esub == 0) {
        float4 b0 = ((const float4*)bias)[c * 2];
        float4 b1 = ((const float4*)bias)[c * 2 + 1];
        float4 o0 = make_float4(a[0]+b0.x, a[1]+b0.y, a[2]+b0.z, a[3]+b0.w);
        float4 o1 = make_float4(a[4]+b1.x, a[5]+b1.y, a[6]+b1.z, a[7]+b1.w);
        o0.x = o0.x > 0.f ? o0.x : 0.f;  o0.y = o0.y > 0.f ? o0.y : 0.f;
        o0.z = o0.z > 0.f ? o0.z : 0.f;  o0.w = o0.w > 0.f ? o0.w : 0.f;
        o1.x = o1.x > 0.f ? o1.x : 0.f;  o1.y = o1.y > 0.f ? o1.y : 0.f;
        o1.z = o1.z > 0.f ? o1.z : 0.f;  o1.w = o1.w > 0.f ? o1.w : 0.f;
        ((float4*)outf)[(size_t)nd * 32 + c * 2]     = o0;
        ((float4*)outf)[(size_t)nd * 32 + c * 2 + 1] = o1;
    }
}

// ---------- gather H=1, C=16; h is bf16; writes fp32 d_out ----------
// pass3: 8 edge-subgroups x 8 lanes, lane owns 2 channels (one uint of bf16)
__global__ void k_gather1(const int* __restrict__ rowptr, const int* __restrict__ col,
                          const float* __restrict__ es, const float* __restrict__ ed,
                          const unsigned short* __restrict__ hfeat,
                          const float* __restrict__ bias, float* __restrict__ outf) {
    const int nd = blockIdx.x * 4 + (threadIdx.x >> 6);
    if (nd >= NODES) return;
    const int lane = threadIdx.x & 63;
    const int start = rowptr[nd], deg = rowptr[nd + 1] - start;

    const float edv = ed[nd];
    float m = -1e30f, sm = 0.f;
    for (int e = lane; e < deg; e += 64) {
        float v = es[col[start + e]] + edv;
        v = v > 0.f ? v : 0.2f * v;
        m = fmaxf(m, v);
    }
    for (int off = 1; off < 64; off <<= 1) m = fmaxf(m, __shfl_xor(m, off));
    for (int e = lane; e < deg; e += 64) {
        float v = es[col[start + e]] + edv;
        v = v > 0.f ? v : 0.2f * v;
        sm += __expf(v - m);
    }
    for (int off = 1; off < 64; off <<= 1) sm += __shfl_xor(sm, off);
    sm = 1.f / (sm + 1e-16f);

    const int esub = lane >> 3;          // 0..7
    const int c = lane & 7;              // lane owns channels 2c, 2c+1
    const unsigned* __restrict__ h1 = (const unsigned*)hfeat;  // bf16 row = 8 uints
    float a0 = 0.f, a1 = 0.f;
    int e = esub;
    for (; e + 8 < deg; e += 16) {
        int s0 = col[start + e];
        int s1 = col[start + e + 8];
        unsigned u0 = h1[(size_t)s0 * 8 + c];
        unsigned u1 = h1[(size_t)s1 * 8 + c];
        float v0 = es[s0] + edv; v0 = v0 > 0.f ? v0 : 0.2f * v0;
        float v1 = es[s1] + edv; v1 = v1 > 0.f ? v1 : 0.2f * v1;
        float al0 = __expf(v0 - m) * sm;
        float al1 = __expf(v1 - m) * sm;
        a0 += al0 * bflo(u0) + al1 * bflo(u1);
        a1 += al0 * bfhi(u0) + al1 * bfhi(u1);
    }
    for (; e < deg; e += 8) {
        int s0 = col[start + e];
        unsigned u0 = h1[(size_t)s0 * 8 + c];
        float v0 = es[s0] + edv; v0 = v0 > 0.f ? v0 : 0.2f * v0;
        float al0 = __expf(v0 - m) * sm;
        a0 += al0 * bflo(u0);
        a1 += al0 * bfhi(u0);
    }
    a0 += __shfl_xor(a0, 8);  a1 += __shfl_xor(a1, 8);
    a0 += __shfl_xor(a0, 16); a1 += __shfl_xor(a1, 16);
    a0 += __shfl_xor(a0, 32); a1 += __shfl_xor(a1, 32);
    if (lane < 8) {
        float2 b = ((const float2*)bias)[c];
        ((float2*)outf)[(size_t)nd * 8 + c] = make_float2(a0 + b.x, a1 + b.y);
    }
}

static inline int gs(long n) { return (int)((n + 255) / 256); }

extern "C" void kernel_launch(void* const* d_in, const int* in_sizes, int n_in,
                              void* d_out, int out_size, void* d_ws, size_t ws_size,
                              hipStream_t stream) {
    const int* ei = (const int*)d_in[1];
    float* out = (float*)d_out;

    char* p = (char*)d_ws;
    float*          Xc     = (float*)p;          p += (size_t)NODES * 128 * 4;
    unsigned short* A      = (unsigned short*)p; p += (size_t)NODES * 128 * 2;  // bf16 h
    float*          es     = (float*)p;          p += (size_t)NODES * 4 * 4;
    float*          ed     = (float*)p;          p += (size_t)NODES * 4 * 4;
    float*          Wc     = (float*)p;          p += (size_t)W_TOTAL * 4;
    int*            deg    = (int*)p;            p += (size_t)NODES * 4;
    int*            rowptr = (int*)p;            p += (size_t)(NODES + 1) * 4;
    int*            col    = (int*)p;            p += (size_t)EPLUS * 4;
    int*            partial= (int*)p;            p += (size_t)NBLK * 4;
    int*            flags  = (int*)p;

    k_detect<<<1, 64, 0, stream>>>((const unsigned*)d_in[0], ei, flags);
    k_cvt_x<<<gs((long)NODES * 128), 256, 0, stream>>>(d_in[0], flags, Xc);
    k_cvt_w<<<gs(W_TOTAL), 256, 0, stream>>>(d_in[2], d_in[3], d_in[4], d_in[5],
                                             d_in[6], d_in[7], d_in[8], d_in[9],
                                             d_in[10], d_in[11], d_in[12], d_in[13],
                                             flags, Wc);

    hipMemsetAsync(deg, 0, (size_t)NODES * 4, stream);
    k_deg<<<gs(EPLUS), 256, 0, stream>>>(ei, flags, deg);
    k_scan_a<<<NBLK, 256, 0, stream>>>(deg, partial);
    k_scan_b<<<1, 256, 0, stream>>>(partial);
    k_scan_c<<<NBLK, 256, 0, stream>>>(deg, partial, rowptr);
    k_fill<<<gs(EPLUS), 256, 0, stream>>>(ei, flags, deg, col);

    const int ggrid = (NODES + 3) / 4;
    const int gemmgrid = (NODES + 127) / 128;   // 391

    k_gemm128<<<gemmgrid, 256, 0, stream>>>(Xc, Wc + O_W1, Wc + O_AS1, Wc + O_AD1, A, es, ed);
    k_gather4<<<ggrid, 256, 0, stream>>>(rowptr, col, es, ed, A, Wc + O_B1, Xc);
    k_gemm128<<<gemmgrid, 256, 0, stream>>>(Xc, Wc + O_W2, Wc + O_AS2, Wc + O_AD2, A, es, ed);
    k_gather4<<<ggrid, 256, 0, stream>>>(rowptr, col, es, ed, A, Wc + O_B2, Xc);
    k_gemm16<<<gemmgrid, 256, 0, stream>>>(Xc, Wc + O_W3, Wc + O_AS3, Wc + O_AD3, A, es, ed);
    k_gather1<<<ggrid, 256, 0, stream>>>(rowptr, col, es, ed, A, Wc + O_B3, out);
}